// Round 7
// baseline (1019.102 us; speedup 1.0000x reference)
//
#include <hip/hip_runtime.h>

typedef _Float16 f16;
typedef __attribute__((ext_vector_type(8))) _Float16 half8;
typedef __attribute__((ext_vector_type(4))) float floatx4;

#define BB    16
#define TSN   16
#define NNP   4096
#define HID   64
#define KPK   224     // 6 k-tiles of 32 (h taps) + 1 k-tile (x taps, 3 live)
#define WOUT  128     // valid output positions per block
#define HALO  16      // time-halo: redundant compute, shrinks 1/step
#define WCMP  160     // computed rows per step = WOUT + 2*HALO (10 m-tiles)
#define HROWS 162     // h-buffer rows = WCMP + 2 (conv halo)
#define NTIL  32

// LDS h layout: row stride 64 f16 (128 B == 0 mod 32 banks), 16B chunk
// XOR-swizzled by row (phys_chunk = chunk ^ (row&7)) -> b128 reads balanced,
// dword epilogue writes 2-way (free). [verified R5: conflicts 8.3M -> 229K]
__device__ __forceinline__ int hadr(int rr, int c) {   // f16 index
    return rr * 64 + ((c ^ (rr & 7)) << 3);
}
__device__ __forceinline__ unsigned f16pair(float a, float b) {
    union { f16 h; unsigned short u; } ua, ub;
    ua.h = (f16)a; ub.h = (f16)b;
    return (unsigned)ua.u | ((unsigned)ub.u << 16);
}

// ---------------------------------------------------------------------------
// Pack conv_w (OIHW 256x65x3x3, only kw=1 live) -> f16 wpack[oc][k]:
//   k = kt*32+c;  kt<6: tap=kt>>1, ch j=(kt&1)*32+c;  kt=6: c<3 -> x tap c.
// ---------------------------------------------------------------------------
__global__ void pack_w_kernel(const float* __restrict__ conv_w, f16* __restrict__ wpack) {
    int idx = blockIdx.x * 256 + threadIdx.x;
    if (idx >= 4 * 64 * KPK) return;
    int k  = idx % KPK;
    int oc = idx / KPK;
    int kt = k >> 5, c = k & 31;
    float w = 0.0f;
    if (kt < 6) {
        int tap = kt >> 1;
        int j   = (kt & 1) * 32 + c;
        w = conv_w[((oc * 65 + 1 + j) * 3 + tap) * 3 + 1];
    } else if (c < 3) {
        w = conv_w[((oc * 65 + 0) * 3 + c) * 3 + 1];
    }
    wpack[oc * KPK + k] = (f16)w;
}

__device__ __forceinline__ float sigmoid_f(float v) { return 1.0f / (1.0f + __expf(-v)); }
__device__ __forceinline__ float tanh_f(float v) { float e = __expf(2.0f * v); return 1.0f - 2.0f / (e + 1.0f); }

// ---------------------------------------------------------------------------
// Self-contained ConvLSTM: 512 independent blocks, NO inter-block sync.
// Block = 512 thr (8 waves): wave w -> hid slice (w&3)*16..+16, m-tile half
// (w>>2) (5 of 10 tiles). Each block: batch b, valid outputs [n0, n0+128),
// computes a fixed 160-row window [n0-16, n0+144) every step; outer shell
// is garbage shrinking inward 1 row/step, never read for valid rows. h rows
// masked to 0 outside [0,NNP). Weights/bias/c in registers for all 16 steps;
// h ping-pongs between two swizzled LDS buffers. 8 waves/block doubles
// waves/SIMD (2->4) vs R6 for latency hiding at identical total work.
// ---------------------------------------------------------------------------
__global__ __launch_bounds__(512, 4)
void lstm_kernel(const float* __restrict__ x, const f16* __restrict__ wpack,
                 const float* __restrict__ conv_b, f16* __restrict__ h_out)
{
    __shared__ __align__(16) f16 hlds[2][HROWS * 64];
    __shared__ __align__(16) f16 xt[WCMP * 8];

    const int blk  = blockIdx.x;
    const int b    = blk >> 5;
    const int tau  = blk & 31;
    const int n0   = tau * WOUT;
    const int tid  = threadIdx.x;
    const int lane = tid & 63;
    const int wave = tid >> 6;
    const int m    = lane & 15;
    const int kg   = lane >> 4;
    const int hid_col = (wave & 3) * 16 + m;
    const int mhalf   = wave >> 2;           // 0: tiles 0-4, 1: tiles 5-9
    const bool edge   = (tau == 0) || (tau == NTIL - 1);

    // B fragments: 7 k-tiles x 4 gates, resident for all steps
    half8 bf[7][4];
#pragma unroll
    for (int kt = 0; kt < 7; ++kt)
#pragma unroll
        for (int g = 0; g < 4; ++g)
            bf[kt][g] = *(const half8*)(wpack + (g * 64 + hid_col) * KPK + kt * 32 + kg * 8);

    float bias[4];
#pragma unroll
    for (int g = 0; g < 4; ++g) bias[g] = conv_b[g * 64 + hid_col];

    // c in registers: creg[mi*4+r] <-> pos n0-HALO + (mhalf*5+mi)*16 + kg*4 + r
    float creg[20];
#pragma unroll
    for (int i = 0; i < 20; ++i) creg[i] = 0.0f;

    // zero both h buffers (h(0)=0; rows 0/161 stay 0 forever) and xt
    for (int i = tid; i < HROWS * 64; i += 512) { hlds[0][i] = (f16)0; hlds[1][i] = (f16)0; }
    for (int i = tid; i < WCMP * 4; i += 512) ((unsigned*)xt)[i] = 0u;
    __syncthreads();

#pragma unroll 1
    for (int s = 0; s < TSN; ++s) {
        const f16* hrd = hlds[s & 1];
        f16*       hwr = hlds[(s & 1) ^ 1];

        // stage x(s): xt row r <-> pos p = n0-HALO+r, taps p-1,p,p+1 (chunk 0)
        if (tid < WCMP) {
            const float* xb = x + ((size_t)b * TSN + s) * NNP;
            int r = tid;
            int p = n0 - HALO + r;
            float v0 = (p - 1 >= 0 && p - 1 < NNP) ? xb[p - 1] : 0.0f;
            float v1 = (p >= 0 && p < NNP) ? xb[p] : 0.0f;
            float v2 = (p + 1 >= 0 && p + 1 < NNP) ? xb[p + 1] : 0.0f;
            ((unsigned*)xt)[r * 4] = f16pair(v0, v1);
            xt[r * 8 + 2] = (f16)v2;
        }
        __syncthreads();   // barrier 1: staging done, prev-step xt readers done

#pragma unroll
        for (int mi = 0; mi < 5; ++mi) {
            const int ms = mhalf * 5 + mi;
            const int ar = ms * 16 + m;    // compute-window row of this lane

            floatx4 acc[4];
#pragma unroll
            for (int g = 0; g < 4; ++g) acc[g] = (floatx4){0.f, 0.f, 0.f, 0.f};

#pragma unroll
            for (int kt = 0; kt < 6; ++kt) {
                // h row rr = ar + tap  (h row 0 <-> pos n0-HALO-1)
                half8 a = *(const half8*)(hrd + hadr(ar + (kt >> 1), (kt & 1) * 4 + kg));
#pragma unroll
                for (int g = 0; g < 4; ++g)
                    acc[g] = __builtin_amdgcn_mfma_f32_16x16x32_f16(a, bf[kt][g], acc[g], 0, 0, 0);
            }
            {
                // x k-tile: all kg read chunk 0 of row ar; k>=3 weights are 0
                half8 a = *(const half8*)(xt + ar * 8);
#pragma unroll
                for (int g = 0; g < 4; ++g)
                    acc[g] = __builtin_amdgcn_mfma_f32_16x16x32_f16(a, bf[6][g], acc[g], 0, 0, 0);
            }

            // epilogue: lane owns (4 rows, hid_col, all gates)
#pragma unroll
            for (int r = 0; r < 4; ++r) {
                int ridx = mi * 4 + r;
                float gi = acc[0][r] + bias[0];
                float gf = acc[1][r] + bias[1];
                float go = acc[2][r] + bias[2];
                float gg = acc[3][r] + bias[3];
                float cn = sigmoid_f(gf) * creg[ridx] + sigmoid_f(gi) * tanh_f(gg);
                float hnf = sigmoid_f(go) * tanh_f(cn);
                creg[ridx] = cn;
                int rit = ms * 16 + kg * 4 + r;        // compute-window row
                if (edge) {
                    int pos = n0 - HALO + rit;
                    if (pos < 0 || pos >= NNP) hnf = 0.0f; // zero-pad semantics
                }
                float po = __shfl_xor(hnf, 1);         // partner hid_col^1
                if (!(m & 1)) {                        // even lane packs dword
                    int rr = rit + 1;
                    int c  = hid_col >> 3;
                    ((unsigned*)hwr)[rr * 32 + (c ^ (rr & 7)) * 4 + ((m & 7) >> 1)] =
                        f16pair(hnf, po);
                }
            }
        }
        __syncthreads();   // barrier 2: hwr complete before it becomes hrd
    }

    // final h(16) is in hlds[0]; valid rows: pos n0+row <-> rr = row+HALO+1.
    // Coalesced b128 stores (wave writes 1 KiB contiguous).
    for (int i = tid; i < WOUT * 8; i += 512) {
        int row = i >> 3, c = i & 7;
        half8 v = *(const half8*)(hlds[0] + hadr(row + HALO + 1, c));
        *(half8*)(h_out + ((size_t)b * NNP + n0 + row) * HID + c * 8) = v;
    }
}

// ---------------------------------------------------------------------------
// fc: out[b,t,n] = sum_hid h[b][n][hid]*fc_w[hid] + fc_b, broadcast over t
// ---------------------------------------------------------------------------
__global__ void fc_kernel(const f16* __restrict__ h, const float* __restrict__ fc_w,
                          const float* __restrict__ fc_b, float* __restrict__ out) {
    int idx = blockIdx.x * 256 + threadIdx.x;      // b*NNP + n
    const half8* hp = (const half8*)(h + (size_t)idx * HID);
    float s = 0.0f;
#pragma unroll
    for (int q = 0; q < 8; ++q) {
        half8 v = hp[q];
#pragma unroll
        for (int e = 0; e < 8; ++e) s += (float)v[e] * fc_w[q * 8 + e];
    }
    s += fc_b[0];
    int b = idx >> 12, n = idx & (NNP - 1);
#pragma unroll
    for (int t = 0; t < TSN; ++t) out[((size_t)b * TSN + t) * NNP + n] = s;
}

extern "C" void kernel_launch(void* const* d_in, const int* in_sizes, int n_in,
                              void* d_out, int out_size, void* d_ws, size_t ws_size,
                              hipStream_t stream) {
    const float* x      = (const float*)d_in[0];
    const float* conv_w = (const float*)d_in[1];
    const float* conv_b = (const float*)d_in[2];
    const float* fc_w   = (const float*)d_in[3];
    const float* fc_b   = (const float*)d_in[4];
    float* out = (float*)d_out;

    char* ws = (char*)d_ws;
    f16* wpack = (f16*)ws;                    // 4*64*224*2 = 112 KiB
    f16* h_a   = (f16*)(ws + 131072);         // 8.39 MB

    pack_w_kernel<<<(4 * 64 * KPK + 255) / 256, 256, 0, stream>>>(conv_w, wpack);
    lstm_kernel<<<BB * NTIL, 512, 0, stream>>>(x, wpack, conv_b, h_a);
    fc_kernel<<<BB * NNP / 256, 256, 0, stream>>>(h_a, fc_w, fc_b, out);
}

// Round 8
// 652.946 us; speedup vs baseline: 1.5608x; 1.5608x over previous
//
#include <hip/hip_runtime.h>

typedef _Float16 f16;
typedef __attribute__((ext_vector_type(8))) _Float16 half8;
typedef __attribute__((ext_vector_type(4))) float floatx4;

#define BB    16
#define TSN   16
#define NNP   4096
#define HID   64
#define KPK   224     // 6 k-tiles of 32 (h taps) + 1 k-tile (x taps, 3 live)
#define WOUT  128     // valid output positions per block
#define HALO  16      // time-halo: redundant compute, shrinks 1/step
#define WCMP  160     // computed rows per step = WOUT + 2*HALO (10 m-tiles)
#define HROWS 162     // h-buffer rows = WCMP + 2 (conv halo)
#define NTIL  32

// LDS h layout: row stride 64 f16 (128 B == 0 mod 32 banks), 16B chunk
// XOR-swizzled by row (phys_chunk = chunk ^ (row&7)) -> b128 reads balanced,
// dword epilogue writes 2-way (free). [verified R5: conflicts 8.3M -> 229K]
__device__ __forceinline__ int hadr(int rr, int c) {   // f16 index
    return rr * 64 + ((c ^ (rr & 7)) << 3);
}
__device__ __forceinline__ unsigned f16pair(float a, float b) {
    union { f16 h; unsigned short u; } ua, ub;
    ua.h = (f16)a; ub.h = (f16)b;
    return (unsigned)ua.u | ((unsigned)ub.u << 16);
}

// ---------------------------------------------------------------------------
// Pack conv_w (OIHW 256x65x3x3, only kw=1 live) -> f16 wpack[oc][k]:
//   k = kt*32+c;  kt<6: tap=kt>>1, ch j=(kt&1)*32+c;  kt=6: c<3 -> x tap c.
// ---------------------------------------------------------------------------
__global__ void pack_w_kernel(const float* __restrict__ conv_w, f16* __restrict__ wpack) {
    int idx = blockIdx.x * 256 + threadIdx.x;
    if (idx >= 4 * 64 * KPK) return;
    int k  = idx % KPK;
    int oc = idx / KPK;
    int kt = k >> 5, c = k & 31;
    float w = 0.0f;
    if (kt < 6) {
        int tap = kt >> 1;
        int j   = (kt & 1) * 32 + c;
        w = conv_w[((oc * 65 + 1 + j) * 3 + tap) * 3 + 1];
    } else if (c < 3) {
        w = conv_w[((oc * 65 + 0) * 3 + c) * 3 + 1];
    }
    wpack[oc * KPK + k] = (f16)w;
}

__device__ __forceinline__ float sigmoid_f(float v) { return 1.0f / (1.0f + __expf(-v)); }
__device__ __forceinline__ float tanh_f(float v) { float e = __expf(2.0f * v); return 1.0f - 2.0f / (e + 1.0f); }

// ---------------------------------------------------------------------------
// Self-contained ConvLSTM: 512 independent blocks, NO inter-block sync.
// Block = 512 thr (8 waves): wave w -> hid slice (w>>1)*16, GATE PAIR w&1
// (gp0: i,f / gp1: o,g). Per-wave resident weights: 7 kt x 2 gates = 56
// VGPRs (vs 112 for 4 gates) -> live set ~105 fits 128 -> 4 waves/SIMD.
// Per m-tile: both gp waves MFMA their 2 gates; the non-owner (gp0 owns
// ms 0-4, gp1 owns ms 5-9 -> transcendental load balanced) publishes its
// float2 gate pair to a parity-double-buffered lane-indexed LDS buffer;
// one block barrier; owner combines all 4 gates, updates c (regs) and
// writes h(t) to the swizzled write buffer. Block covers batch b, valid
// outputs [n0,n0+128), computed window 160 rows (halo-16 recompute, R6).
// ---------------------------------------------------------------------------
__global__ __launch_bounds__(512, 2)
void lstm_kernel(const float* __restrict__ x, const f16* __restrict__ wpack,
                 const float* __restrict__ conv_b, f16* __restrict__ h_out)
{
    __shared__ __align__(16) f16 hlds[2][HROWS * 64];
    __shared__ __align__(16) f16 xt[WCMP * 8];
    __shared__ __align__(16) float gx[2][4][4][64][2];   // [par][hs][r][lane][g2] 16KB

    const int blk  = blockIdx.x;
    const int b    = blk >> 5;
    const int tau  = blk & 31;
    const int n0   = tau * WOUT;
    const int tid  = threadIdx.x;
    const int lane = tid & 63;
    const int wave = tid >> 6;
    const int m    = lane & 15;
    const int kg   = lane >> 4;
    const int hs   = wave >> 1;            // hid slice 0..3
    const int gp   = wave & 1;             // 0: gates i,f   1: gates o,g
    const int hid_col = hs * 16 + m;
    const bool edge   = (tau == 0) || (tau == NTIL - 1);

    // B fragments: 7 k-tiles x 2 gates (own pair), resident for all steps
    half8 bf[7][2];
#pragma unroll
    for (int kt = 0; kt < 7; ++kt)
#pragma unroll
        for (int gg = 0; gg < 2; ++gg)
            bf[kt][gg] = *(const half8*)(wpack + ((gp * 2 + gg) * 64 + hid_col) * KPK + kt * 32 + kg * 8);

    float bias[4];
#pragma unroll
    for (int g = 0; g < 4; ++g) bias[g] = conv_b[g * 64 + hid_col];

    // c in registers for OWNED m-tiles: gp0 -> ms 0-4, gp1 -> ms 5-9.
    // creg[mi*4+r] <-> row = (gp*5+mi)*16 + kg*4 + r
    float creg[20];
#pragma unroll
    for (int i = 0; i < 20; ++i) creg[i] = 0.0f;

    // zero both h buffers (h(0)=0; rows 0/161 stay 0 forever) and xt
    for (int i = tid; i < HROWS * 64; i += 512) { hlds[0][i] = (f16)0; hlds[1][i] = (f16)0; }
    for (int i = tid; i < WCMP * 4; i += 512) ((unsigned*)xt)[i] = 0u;
    __syncthreads();

#pragma unroll 1
    for (int s = 0; s < TSN; ++s) {
        const f16* hrd = hlds[s & 1];
        f16*       hwr = hlds[(s & 1) ^ 1];

        // stage x(s): xt row r <-> pos p = n0-HALO+r, taps p-1,p,p+1 (chunk 0)
        if (tid < WCMP) {
            const float* xb = x + ((size_t)b * TSN + s) * NNP;
            int r = tid;
            int p = n0 - HALO + r;
            float v0 = (p - 1 >= 0 && p - 1 < NNP) ? xb[p - 1] : 0.0f;
            float v1 = (p >= 0 && p < NNP) ? xb[p] : 0.0f;
            float v2 = (p + 1 >= 0 && p + 1 < NNP) ? xb[p + 1] : 0.0f;
            ((unsigned*)xt)[r * 4] = f16pair(v0, v1);
            xt[r * 8 + 2] = (f16)v2;
        }
        __syncthreads();   // barrier A: staging done; prev step's epi writes done

#pragma unroll
        for (int ms = 0; ms < 10; ++ms) {
            const int ar = ms * 16 + m;    // compute-window row of this lane

            floatx4 acc[2];
            acc[0] = (floatx4){0.f, 0.f, 0.f, 0.f};
            acc[1] = (floatx4){0.f, 0.f, 0.f, 0.f};

#pragma unroll
            for (int kt = 0; kt < 6; ++kt) {
                half8 a = *(const half8*)(hrd + hadr(ar + (kt >> 1), (kt & 1) * 4 + kg));
                acc[0] = __builtin_amdgcn_mfma_f32_16x16x32_f16(a, bf[kt][0], acc[0], 0, 0, 0);
                acc[1] = __builtin_amdgcn_mfma_f32_16x16x32_f16(a, bf[kt][1], acc[1], 0, 0, 0);
            }
            {
                half8 a = *(const half8*)(xt + ar * 8);
                acc[0] = __builtin_amdgcn_mfma_f32_16x16x32_f16(a, bf[6][0], acc[0], 0, 0, 0);
                acc[1] = __builtin_amdgcn_mfma_f32_16x16x32_f16(a, bf[6][1], acc[1], 0, 0, 0);
            }

            const bool owner = (ms < 5) ? (gp == 0) : (gp == 1);
            if (!owner) {
                // publish gate pair (lane-indexed, stride-8B -> conflict-free)
#pragma unroll
                for (int r = 0; r < 4; ++r)
                    *(float2*)&gx[ms & 1][hs][r][lane][0] = make_float2(acc[0][r], acc[1][r]);
            }
            __syncthreads();   // partner's gates visible
            if (owner) {
                const int mi = (ms < 5) ? ms : ms - 5;
#pragma unroll
                for (int r = 0; r < 4; ++r) {
                    float2 pg = *(const float2*)&gx[ms & 1][hs][r][lane][0];
                    float gi, gf, go, gg2;
                    if (gp == 0) { gi = acc[0][r]; gf = acc[1][r]; go = pg.x; gg2 = pg.y; }
                    else         { gi = pg.x;      gf = pg.y;      go = acc[0][r]; gg2 = acc[1][r]; }
                    gi += bias[0]; gf += bias[1]; go += bias[2]; gg2 += bias[3];
                    int ridx = mi * 4 + r;
                    float cn  = sigmoid_f(gf) * creg[ridx] + sigmoid_f(gi) * tanh_f(gg2);
                    float hnf = sigmoid_f(go) * tanh_f(cn);
                    creg[ridx] = cn;
                    int rit = ms * 16 + kg * 4 + r;        // compute-window row
                    if (edge) {
                        int pos = n0 - HALO + rit;
                        if (pos < 0 || pos >= NNP) hnf = 0.0f; // zero-pad semantics
                    }
                    float po = __shfl_xor(hnf, 1);         // partner hid_col^1
                    if (!(m & 1)) {                        // even lane packs dword
                        int rr = rit + 1;
                        int c  = hid_col >> 3;
                        ((unsigned*)hwr)[rr * 32 + (c ^ (rr & 7)) * 4 + ((m & 7) >> 1)] =
                            f16pair(hnf, po);
                    }
                }
            }
        }
        // owners finish epi(ms=9) before reaching next step's barrier A,
        // which guards both xt restaging and the hrd/hwr swap.
    }

    // final h(16) is in hlds[0]; valid rows: pos n0+row <-> rr = row+HALO+1.
    for (int i = tid; i < WOUT * 8; i += 512) {
        int row = i >> 3, c = i & 7;
        half8 v = *(const half8*)(hlds[0] + hadr(row + HALO + 1, c));
        *(half8*)(h_out + ((size_t)b * NNP + n0 + row) * HID + c * 8) = v;
    }
}

// ---------------------------------------------------------------------------
// fc: out[b,t,n] = sum_hid h[b][n][hid]*fc_w[hid] + fc_b, broadcast over t
// ---------------------------------------------------------------------------
__global__ void fc_kernel(const f16* __restrict__ h, const float* __restrict__ fc_w,
                          const float* __restrict__ fc_b, float* __restrict__ out) {
    int idx = blockIdx.x * 256 + threadIdx.x;      // b*NNP + n
    const half8* hp = (const half8*)(h + (size_t)idx * HID);
    float s = 0.0f;
#pragma unroll
    for (int q = 0; q < 8; ++q) {
        half8 v = hp[q];
#pragma unroll
        for (int e = 0; e < 8; ++e) s += (float)v[e] * fc_w[q * 8 + e];
    }
    s += fc_b[0];
    int b = idx >> 12, n = idx & (NNP - 1);
#pragma unroll
    for (int t = 0; t < TSN; ++t) out[((size_t)b * TSN + t) * NNP + n] = s;
}

extern "C" void kernel_launch(void* const* d_in, const int* in_sizes, int n_in,
                              void* d_out, int out_size, void* d_ws, size_t ws_size,
                              hipStream_t stream) {
    const float* x      = (const float*)d_in[0];
    const float* conv_w = (const float*)d_in[1];
    const float* conv_b = (const float*)d_in[2];
    const float* fc_w   = (const float*)d_in[3];
    const float* fc_b   = (const float*)d_in[4];
    float* out = (float*)d_out;

    char* ws = (char*)d_ws;
    f16* wpack = (f16*)ws;                    // 4*64*224*2 = 112 KiB
    f16* h_a   = (f16*)(ws + 131072);         // 8.39 MB

    pack_w_kernel<<<(4 * 64 * KPK + 255) / 256, 256, 0, stream>>>(conv_w, wpack);
    lstm_kernel<<<BB * NTIL, 512, 0, stream>>>(x, wpack, conv_b, h_a);
    fc_kernel<<<BB * NNP / 256, 256, 0, stream>>>(h_a, fc_w, fc_b, out);
}

// Round 9
// 399.712 us; speedup vs baseline: 2.5496x; 1.6335x over previous
//
#include <hip/hip_runtime.h>

typedef _Float16 f16;
typedef __attribute__((ext_vector_type(8))) _Float16 half8;
typedef __attribute__((ext_vector_type(4))) float floatx4;

#define BB    16
#define TSN   16
#define NNP   4096
#define HID   64
#define KPK   224     // 6 k-tiles of 32 (h taps) + 1 k-tile (x taps, 3 live)
#define WOUT  128     // valid output positions per block
#define HALO  8       // time-halo per 8-step chunk (2 launches)
#define WCMP  144     // computed rows per step = WOUT + 2*HALO (9 m-tiles)
#define HROWS 146     // h-buffer rows = WCMP + 2 (conv halo)
#define NMS   9
#define NTIL  32

// LDS h layout: row stride 64 f16 (128 B == 0 mod 32 banks), 16B chunk
// XOR-swizzled by row (phys_chunk = chunk ^ (row&7)) -> b128 reads balanced,
// dword epilogue writes conflict-light. [verified R5: conflicts 8.3M -> 229K]
__device__ __forceinline__ int hadr(int rr, int c) {   // f16 index
    return rr * 64 + ((c ^ (rr & 7)) << 3);
}
__device__ __forceinline__ unsigned f16pair(float a, float b) {
    union { f16 h; unsigned short u; } ua, ub;
    ua.h = (f16)a; ub.h = (f16)b;
    return (unsigned)ua.u | ((unsigned)ub.u << 16);
}

// ---------------------------------------------------------------------------
// Pack conv_w (OIHW 256x65x3x3, only kw=1 live) -> f16 wpack[oc][k]:
//   k = kt*32+c;  kt<6: tap=kt>>1, ch j=(kt&1)*32+c;  kt=6: c<3 -> x tap c.
// ---------------------------------------------------------------------------
__global__ void pack_w_kernel(const float* __restrict__ conv_w, f16* __restrict__ wpack) {
    int idx = blockIdx.x * 256 + threadIdx.x;
    if (idx >= 4 * 64 * KPK) return;
    int k  = idx % KPK;
    int oc = idx / KPK;
    int kt = k >> 5, c = k & 31;
    float w = 0.0f;
    if (kt < 6) {
        int tap = kt >> 1;
        int j   = (kt & 1) * 32 + c;
        w = conv_w[((oc * 65 + 1 + j) * 3 + tap) * 3 + 1];
    } else if (c < 3) {
        w = conv_w[((oc * 65 + 0) * 3 + c) * 3 + 1];
    }
    wpack[oc * KPK + k] = (f16)w;
}

__device__ __forceinline__ float sigmoid_f(float v) { return 1.0f / (1.0f + __expf(-v)); }
__device__ __forceinline__ float tanh_f(float v) { float e = __expf(2.0f * v); return 1.0f - 2.0f / (e + 1.0f); }

// ---------------------------------------------------------------------------
// ConvLSTM 8-step chunk, 512 independent blocks, NO inter-block sync.
// Block = 512 thr (8 waves). Gate-packed MFMA N-dim: call q in {0,1} has
// column n -> gate q*2+(n>>3), hid wave*8+(n&7). Per-wave B-frags: 7 kt x 2
// = 56 VGPR -> amdgpu_waves_per_eu(4) (128-VGPR cap) -> 16 waves/CU.
// Lane pair (m, m+8) holds the two gate-halves of the same (pos,hid);
// gates exchanged via shfl_xor(8) (no LDS/barriers); the pair splits acc
// rows (m<8: r=0,1 / m>=8: r=2,3) -> no duplicated epilogue work.
// Halo-8 recompute (window 144 rows, shell shrinks 1 row/step; after 8
// steps valid rows = [HALO, HALO+WOUT) exactly). phase 0: h(0)=c(0)=0,
// stores h(8),c(8). phase 1: seeds from h(8),c(8), stores h(16).
// ---------------------------------------------------------------------------
__global__ __attribute__((amdgpu_flat_work_group_size(512, 512), amdgpu_waves_per_eu(4)))
void lstm_kernel(const float* __restrict__ x, const f16* __restrict__ wpack,
                 const float* __restrict__ conv_b,
                 f16* __restrict__ h_glob, float* __restrict__ c_glob, int phase)
{
    __shared__ __align__(16) f16 hlds[2][HROWS * 64];
    __shared__ __align__(16) f16 xt[WCMP * 8];

    const int blk  = blockIdx.x;
    const int b    = blk >> 5;
    const int tau  = blk & 31;
    const int n0   = tau * WOUT;
    const int tid  = threadIdx.x;
    const int lane = tid & 63;
    const int wave = tid >> 6;             // 0..7
    const int m    = lane & 15;
    const int kg   = lane >> 4;
    const int gh   = m >> 3;               // gate half of this lane's column
    const int hid  = wave * 8 + (m & 7);
    const bool lowm = (m < 8);
    const bool edge = (tau == 0) || (tau == NTIL - 1);

    // B fragments, gate-packed: bf[kt][q], element k=kg*8+i of column
    // (gate q*2+gh, hid). 14 half8 = 56 VGPR, resident all 8 steps.
    half8 bf[7][2];
#pragma unroll
    for (int kt = 0; kt < 7; ++kt)
#pragma unroll
        for (int q = 0; q < 2; ++q)
            bf[kt][q] = *(const half8*)(wpack + (size_t)((q * 2 + gh) * 64 + hid) * KPK + kt * 32 + kg * 8);

    float bias[4];
#pragma unroll
    for (int g = 0; g < 4; ++g) bias[g] = conv_b[g * 64 + hid];

    // c in regs: creg[ms*2+j] <-> pos = n0-HALO + ms*16 + kg*4 + r,
    // r = lowm ? j : 2+j  (lane pair splits the 4 acc rows)
    float creg[NMS * 2];

    if (phase == 0) {
#pragma unroll
        for (int i = 0; i < NMS * 2; ++i) creg[i] = 0.0f;
        for (int i = tid; i < HROWS * 64; i += 512) { hlds[0][i] = (f16)0; hlds[1][i] = (f16)0; }
    } else {
        // seed h(8) window from global (rr <-> pos n0-HALO-1+rr), OOB -> 0
        for (int i = tid; i < HROWS * 8; i += 512) {
            int rr = i >> 3, c = i & 7;
            int pos = n0 - HALO - 1 + rr;
            half8 v = {};
            if (pos >= 0 && pos < NNP)
                v = *(const half8*)(h_glob + ((size_t)b * NNP + pos) * HID + c * 8);
            *(half8*)(hlds[0] + hadr(rr, c)) = v;
        }
        for (int i = tid; i < HROWS * 64; i += 512) hlds[1][i] = (f16)0;
        // seed c(8) for the full window (shell rows read neighbors' valid c)
#pragma unroll
        for (int ms = 0; ms < NMS; ++ms)
#pragma unroll
            for (int j = 0; j < 2; ++j) {
                int r   = lowm ? j : 2 + j;
                int pos = n0 - HALO + ms * 16 + kg * 4 + r;
                creg[ms * 2 + j] = (pos >= 0 && pos < NNP)
                    ? c_glob[((size_t)b * NNP + pos) * HID + hid] : 0.0f;
            }
    }
    for (int i = tid; i < WCMP * 4; i += 512) ((unsigned*)xt)[i] = 0u;
    __syncthreads();

    const int s0 = phase * 8;
#pragma unroll 1
    for (int s = s0; s < s0 + 8; ++s) {
        const f16* hrd = hlds[s & 1];
        f16*       hwr = hlds[(s & 1) ^ 1];

        // stage x(s): xt row r <-> pos p = n0-HALO+r, taps p-1,p,p+1
        if (tid < WCMP) {
            const float* xb = x + ((size_t)b * TSN + s) * NNP;
            int r = tid;
            int p = n0 - HALO + r;
            float v0 = (p - 1 >= 0 && p - 1 < NNP) ? xb[p - 1] : 0.0f;
            float v1 = (p >= 0 && p < NNP) ? xb[p] : 0.0f;
            float v2 = (p + 1 >= 0 && p + 1 < NNP) ? xb[p + 1] : 0.0f;
            ((unsigned*)xt)[r * 4] = f16pair(v0, v1);
            xt[r * 8 + 2] = (f16)v2;
        }
        __syncthreads();   // barrier 1: staging visible; prev-step readers done

#pragma unroll
        for (int ms = 0; ms < NMS; ++ms) {
            const int ar = ms * 16 + m;    // compute-window row of this lane

            floatx4 acc[2];
            acc[0] = (floatx4){0.f, 0.f, 0.f, 0.f};
            acc[1] = (floatx4){0.f, 0.f, 0.f, 0.f};

#pragma unroll
            for (int kt = 0; kt < 6; ++kt) {
                half8 a = *(const half8*)(hrd + hadr(ar + (kt >> 1), (kt & 1) * 4 + kg));
                acc[0] = __builtin_amdgcn_mfma_f32_16x16x32_f16(a, bf[kt][0], acc[0], 0, 0, 0);
                acc[1] = __builtin_amdgcn_mfma_f32_16x16x32_f16(a, bf[kt][1], acc[1], 0, 0, 0);
            }
            {
                // x k-tile: k>=3 weights are 0, so all kg read chunk 0
                half8 a = *(const half8*)(xt + ar * 8);
                acc[0] = __builtin_amdgcn_mfma_f32_16x16x32_f16(a, bf[6][0], acc[0], 0, 0, 0);
                acc[1] = __builtin_amdgcn_mfma_f32_16x16x32_f16(a, bf[6][1], acc[1], 0, 0, 0);
            }

            // gate exchange across the m/m+8 pair; pair splits rows
            float pg[2][2];
#pragma unroll
            for (int q = 0; q < 2; ++q)
#pragma unroll
                for (int j = 0; j < 2; ++j) {
                    float send = lowm ? acc[q][2 + j] : acc[q][j];
                    pg[q][j] = __shfl_xor(send, 8);
                }

#pragma unroll
            for (int j = 0; j < 2; ++j) {
                int r  = lowm ? j : 2 + j;
                float gi = (lowm ? acc[0][j] : pg[0][j]) + bias[0];
                float gf = (lowm ? pg[0][j] : acc[0][2 + j]) + bias[1];
                float go = (lowm ? acc[1][j] : pg[1][j]) + bias[2];
                float gg = (lowm ? pg[1][j] : acc[1][2 + j]) + bias[3];
                int ridx = ms * 2 + j;
                float cn  = sigmoid_f(gf) * creg[ridx] + sigmoid_f(gi) * tanh_f(gg);
                float hnf = sigmoid_f(go) * tanh_f(cn);
                creg[ridx] = cn;
                int rit = ms * 16 + kg * 4 + r;        // compute-window row
                if (edge) {
                    int pos = n0 - HALO + rit;
                    if (pos < 0 || pos >= NNP) hnf = 0.0f;  // zero-pad semantics
                }
                float po = __shfl_xor(hnf, 1);          // partner hid^1
                if (!(m & 1)) {                          // even lane packs dword
                    int rr = rit + 1;
                    ((unsigned*)hwr)[rr * 32 + ((wave ^ (rr & 7)) << 2) + ((m & 7) >> 1)] =
                        f16pair(hnf, po);
                }
            }
        }
        __syncthreads();   // barrier 2: hwr complete before it becomes hrd
    }

    // h(s0+8) is in hlds[0] (last step is odd); valid rows rr = row+HALO+1.
    for (int i = tid; i < WOUT * 8; i += 512) {
        int row = i >> 3, c = i & 7;
        half8 v = *(const half8*)(hlds[0] + hadr(row + HALO + 1, c));
        *(half8*)(h_glob + ((size_t)b * NNP + n0 + row) * HID + c * 8) = v;
    }
    if (phase == 0) {
        // persist c(8) for valid rows
#pragma unroll
        for (int ms = 0; ms < NMS; ++ms)
#pragma unroll
            for (int j = 0; j < 2; ++j) {
                int r   = lowm ? j : 2 + j;
                int rit = ms * 16 + kg * 4 + r;
                int pos = n0 - HALO + rit;
                if (rit >= HALO && rit < HALO + WOUT && pos >= 0 && pos < NNP)
                    c_glob[((size_t)b * NNP + pos) * HID + hid] = creg[ms * 2 + j];
            }
    }
}

// ---------------------------------------------------------------------------
// fc: out[b,t,n] = sum_hid h[b][n][hid]*fc_w[hid] + fc_b, broadcast over t
// ---------------------------------------------------------------------------
__global__ void fc_kernel(const f16* __restrict__ h, const float* __restrict__ fc_w,
                          const float* __restrict__ fc_b, float* __restrict__ out) {
    int idx = blockIdx.x * 256 + threadIdx.x;      // b*NNP + n
    const half8* hp = (const half8*)(h + (size_t)idx * HID);
    float s = 0.0f;
#pragma unroll
    for (int q = 0; q < 8; ++q) {
        half8 v = hp[q];
#pragma unroll
        for (int e = 0; e < 8; ++e) s += (float)v[e] * fc_w[q * 8 + e];
    }
    s += fc_b[0];
    int b = idx >> 12, n = idx & (NNP - 1);
#pragma unroll
    for (int t = 0; t < TSN; ++t) out[((size_t)b * TSN + t) * NNP + n] = s;
}

extern "C" void kernel_launch(void* const* d_in, const int* in_sizes, int n_in,
                              void* d_out, int out_size, void* d_ws, size_t ws_size,
                              hipStream_t stream) {
    const float* x      = (const float*)d_in[0];
    const float* conv_w = (const float*)d_in[1];
    const float* conv_b = (const float*)d_in[2];
    const float* fc_w   = (const float*)d_in[3];
    const float* fc_b   = (const float*)d_in[4];
    float* out = (float*)d_out;

    char* ws = (char*)d_ws;
    const size_t hbytes = (size_t)BB * NNP * HID * sizeof(f16);     // 8.39 MB
    f16*   wpack  = (f16*)ws;                                       // 112 KiB
    f16*   h_glob = (f16*)(ws + 131072);
    float* c_glob = (float*)(ws + 131072 + hbytes);                 // 16.8 MB

    pack_w_kernel<<<(4 * 64 * KPK + 255) / 256, 256, 0, stream>>>(conv_w, wpack);
    lstm_kernel<<<BB * NTIL, 512, 0, stream>>>(x, wpack, conv_b, h_glob, c_glob, 0);
    lstm_kernel<<<BB * NTIL, 512, 0, stream>>>(x, wpack, conv_b, h_glob, c_glob, 1);
    fc_kernel<<<BB * NNP / 256, 256, 0, stream>>>(h_glob, fc_w, fc_b, out);
}

// Round 10
// 395.356 us; speedup vs baseline: 2.5777x; 1.0110x over previous
//
#include <hip/hip_runtime.h>

typedef _Float16 f16;
typedef __attribute__((ext_vector_type(8))) _Float16 half8;
typedef __attribute__((ext_vector_type(4))) float floatx4;

#define BB    16
#define TSN   16
#define NNP   4096
#define HID   64
#define KPK   224     // 6 k-tiles of 32 (h taps) + 1 k-tile (x taps, 3 live)
#define WOUT  128     // valid output positions per block
#define HALO  8       // time-halo per 8-step chunk (2 launches)
#define WCMP  144     // computed rows per step = WOUT + 2*HALO (9 m-tiles)
#define HROWS 146     // h-buffer rows = WCMP + 2 (conv halo)
#define NMS   9
#define NTIL  32

// LDS h layout: row stride 64 f16 (128 B == 0 mod 32 banks), 16B chunk
// XOR-swizzled by row (phys_chunk = chunk ^ (row&7)) -> b128 reads balanced,
// dword epilogue writes conflict-light. [verified R5: conflicts 8.3M -> 229K]
__device__ __forceinline__ int hadr(int rr, int c) {   // f16 index
    return rr * 64 + ((c ^ (rr & 7)) << 3);
}
__device__ __forceinline__ unsigned f16pair(float a, float b) {
    union { f16 h; unsigned short u; } ua, ub;
    ua.h = (f16)a; ub.h = (f16)b;
    return (unsigned)ua.u | ((unsigned)ub.u << 16);
}

// ---------------------------------------------------------------------------
// Pack conv_w (OIHW 256x65x3x3, only kw=1 live) -> f16 wpack[oc][k]:
//   k = kt*32+c;  kt<6: tap=kt>>1, ch j=(kt&1)*32+c;  kt=6: c<3 -> x tap c.
// ---------------------------------------------------------------------------
__global__ void pack_w_kernel(const float* __restrict__ conv_w, f16* __restrict__ wpack) {
    int idx = blockIdx.x * 256 + threadIdx.x;
    if (idx >= 4 * 64 * KPK) return;
    int k  = idx % KPK;
    int oc = idx / KPK;
    int kt = k >> 5, c = k & 31;
    float w = 0.0f;
    if (kt < 6) {
        int tap = kt >> 1;
        int j   = (kt & 1) * 32 + c;
        w = conv_w[((oc * 65 + 1 + j) * 3 + tap) * 3 + 1];
    } else if (c < 3) {
        w = conv_w[((oc * 65 + 0) * 3 + c) * 3 + 1];
    }
    wpack[oc * KPK + k] = (f16)w;
}

__device__ __forceinline__ float sigmoid_f(float v) { return 1.0f / (1.0f + __expf(-v)); }
__device__ __forceinline__ float tanh_f(float v) { float e = __expf(2.0f * v); return 1.0f - 2.0f / (e + 1.0f); }

// ---------------------------------------------------------------------------
// ConvLSTM 8-step chunk, 512 independent blocks, NO inter-block sync.
// Block = 512 thr (8 waves). Gate-packed MFMA N-dim: call q in {0,1} has
// column n -> gate q*2+(n>>3), hid wave*8+(n&7). Per-wave B-frags: 7 kt x 2
// = 56 VGPR.  __launch_bounds__(512,2): VGPR cap 256; allocator lands ~124
// (R8-verified on this live set) -> no spills, 4 waves/SIMD at 2 blocks/CU.
// [R9 errata: single-arg amdgpu_waves_per_eu(4) let the heuristic target
//  8 waves/EU -> 64 VGPR -> wholesale spill, FETCH 127 MB/dispatch.]
// Lane pair (m, m+8) holds the two gate-halves of the same (pos,hid);
// gates exchanged via shfl_xor(8) (no LDS/barriers); the pair splits acc
// rows (m<8: r=0,1 / m>=8: r=2,3) -> no duplicated epilogue work.
// Halo-8 recompute (window 144 rows, shell shrinks 1 row/step; after 8
// steps valid rows = [HALO, HALO+WOUT) exactly). phase 0: h(0)=c(0)=0,
// stores h(8),c(8). phase 1: seeds from h(8),c(8), stores h(16).
// ---------------------------------------------------------------------------
__global__ __launch_bounds__(512, 2)
void lstm_kernel(const float* __restrict__ x, const f16* __restrict__ wpack,
                 const float* __restrict__ conv_b,
                 f16* __restrict__ h_glob, float* __restrict__ c_glob, int phase)
{
    __shared__ __align__(16) f16 hlds[2][HROWS * 64];
    __shared__ __align__(16) f16 xt[WCMP * 8];

    const int blk  = blockIdx.x;
    const int b    = blk >> 5;
    const int tau  = blk & 31;
    const int n0   = tau * WOUT;
    const int tid  = threadIdx.x;
    const int lane = tid & 63;
    const int wave = tid >> 6;             // 0..7
    const int m    = lane & 15;
    const int kg   = lane >> 4;
    const int gh   = m >> 3;               // gate half of this lane's column
    const int hid  = wave * 8 + (m & 7);
    const bool lowm = (m < 8);
    const bool edge = (tau == 0) || (tau == NTIL - 1);

    // B fragments, gate-packed: bf[kt][q], element k=kg*8+i of column
    // (gate q*2+gh, hid). 14 half8 = 56 VGPR, resident all 8 steps.
    half8 bf[7][2];
#pragma unroll
    for (int kt = 0; kt < 7; ++kt)
#pragma unroll
        for (int q = 0; q < 2; ++q)
            bf[kt][q] = *(const half8*)(wpack + (size_t)((q * 2 + gh) * 64 + hid) * KPK + kt * 32 + kg * 8);

    float bias[4];
#pragma unroll
    for (int g = 0; g < 4; ++g) bias[g] = conv_b[g * 64 + hid];

    // c in regs: creg[ms*2+j] <-> pos = n0-HALO + ms*16 + kg*4 + r,
    // r = lowm ? j : 2+j  (lane pair splits the 4 acc rows)
    float creg[NMS * 2];

    if (phase == 0) {
#pragma unroll
        for (int i = 0; i < NMS * 2; ++i) creg[i] = 0.0f;
        for (int i = tid; i < HROWS * 64; i += 512) { hlds[0][i] = (f16)0; hlds[1][i] = (f16)0; }
    } else {
        // seed h(8) window from global (rr <-> pos n0-HALO-1+rr), OOB -> 0
        for (int i = tid; i < HROWS * 8; i += 512) {
            int rr = i >> 3, c = i & 7;
            int pos = n0 - HALO - 1 + rr;
            half8 v = {};
            if (pos >= 0 && pos < NNP)
                v = *(const half8*)(h_glob + ((size_t)b * NNP + pos) * HID + c * 8);
            *(half8*)(hlds[0] + hadr(rr, c)) = v;
        }
        for (int i = tid; i < HROWS * 64; i += 512) hlds[1][i] = (f16)0;
        // seed c(8) for the full window (shell rows read neighbors' valid c)
#pragma unroll
        for (int ms = 0; ms < NMS; ++ms)
#pragma unroll
            for (int j = 0; j < 2; ++j) {
                int r   = lowm ? j : 2 + j;
                int pos = n0 - HALO + ms * 16 + kg * 4 + r;
                creg[ms * 2 + j] = (pos >= 0 && pos < NNP)
                    ? c_glob[((size_t)b * NNP + pos) * HID + hid] : 0.0f;
            }
    }
    for (int i = tid; i < WCMP * 4; i += 512) ((unsigned*)xt)[i] = 0u;
    __syncthreads();

    const int s0 = phase * 8;
#pragma unroll 1
    for (int s = s0; s < s0 + 8; ++s) {
        const f16* hrd = hlds[s & 1];
        f16*       hwr = hlds[(s & 1) ^ 1];

        // stage x(s): xt row r <-> pos p = n0-HALO+r, taps p-1,p,p+1
        if (tid < WCMP) {
            const float* xb = x + ((size_t)b * TSN + s) * NNP;
            int r = tid;
            int p = n0 - HALO + r;
            float v0 = (p - 1 >= 0 && p - 1 < NNP) ? xb[p - 1] : 0.0f;
            float v1 = (p >= 0 && p < NNP) ? xb[p] : 0.0f;
            float v2 = (p + 1 >= 0 && p + 1 < NNP) ? xb[p + 1] : 0.0f;
            ((unsigned*)xt)[r * 4] = f16pair(v0, v1);
            xt[r * 8 + 2] = (f16)v2;
        }
        __syncthreads();   // barrier 1: staging visible; prev-step readers done

#pragma unroll
        for (int ms = 0; ms < NMS; ++ms) {
            const int ar = ms * 16 + m;    // compute-window row of this lane

            floatx4 acc[2];
            acc[0] = (floatx4){0.f, 0.f, 0.f, 0.f};
            acc[1] = (floatx4){0.f, 0.f, 0.f, 0.f};

#pragma unroll
            for (int kt = 0; kt < 6; ++kt) {
                half8 a = *(const half8*)(hrd + hadr(ar + (kt >> 1), (kt & 1) * 4 + kg));
                acc[0] = __builtin_amdgcn_mfma_f32_16x16x32_f16(a, bf[kt][0], acc[0], 0, 0, 0);
                acc[1] = __builtin_amdgcn_mfma_f32_16x16x32_f16(a, bf[kt][1], acc[1], 0, 0, 0);
            }
            {
                // x k-tile: k>=3 weights are 0, so all kg read chunk 0
                half8 a = *(const half8*)(xt + ar * 8);
                acc[0] = __builtin_amdgcn_mfma_f32_16x16x32_f16(a, bf[6][0], acc[0], 0, 0, 0);
                acc[1] = __builtin_amdgcn_mfma_f32_16x16x32_f16(a, bf[6][1], acc[1], 0, 0, 0);
            }

            // gate exchange across the m/m+8 pair; pair splits rows
            float pg[2][2];
#pragma unroll
            for (int q = 0; q < 2; ++q)
#pragma unroll
                for (int j = 0; j < 2; ++j) {
                    float send = lowm ? acc[q][2 + j] : acc[q][j];
                    pg[q][j] = __shfl_xor(send, 8);
                }

#pragma unroll
            for (int j = 0; j < 2; ++j) {
                int r  = lowm ? j : 2 + j;
                float gi = (lowm ? acc[0][j] : pg[0][j]) + bias[0];
                float gf = (lowm ? pg[0][j] : acc[0][2 + j]) + bias[1];
                float go = (lowm ? acc[1][j] : pg[1][j]) + bias[2];
                float gg = (lowm ? pg[1][j] : acc[1][2 + j]) + bias[3];
                int ridx = ms * 2 + j;
                float cn  = sigmoid_f(gf) * creg[ridx] + sigmoid_f(gi) * tanh_f(gg);
                float hnf = sigmoid_f(go) * tanh_f(cn);
                creg[ridx] = cn;
                int rit = ms * 16 + kg * 4 + r;        // compute-window row
                if (edge) {
                    int pos = n0 - HALO + rit;
                    if (pos < 0 || pos >= NNP) hnf = 0.0f;  // zero-pad semantics
                }
                float po = __shfl_xor(hnf, 1);          // partner hid^1
                if (!(m & 1)) {                          // even lane packs dword
                    int rr = rit + 1;
                    ((unsigned*)hwr)[rr * 32 + ((wave ^ (rr & 7)) << 2) + ((m & 7) >> 1)] =
                        f16pair(hnf, po);
                }
            }
        }
        __syncthreads();   // barrier 2: hwr complete before it becomes hrd
    }

    // h(s0+8) is in hlds[0] (last step is odd); valid rows rr = row+HALO+1.
    for (int i = tid; i < WOUT * 8; i += 512) {
        int row = i >> 3, c = i & 7;
        half8 v = *(const half8*)(hlds[0] + hadr(row + HALO + 1, c));
        *(half8*)(h_glob + ((size_t)b * NNP + n0 + row) * HID + c * 8) = v;
    }
    if (phase == 0) {
        // persist c(8) for valid rows
#pragma unroll
        for (int ms = 0; ms < NMS; ++ms)
#pragma unroll
            for (int j = 0; j < 2; ++j) {
                int r   = lowm ? j : 2 + j;
                int rit = ms * 16 + kg * 4 + r;
                int pos = n0 - HALO + rit;
                if (rit >= HALO && rit < HALO + WOUT && pos >= 0 && pos < NNP)
                    c_glob[((size_t)b * NNP + pos) * HID + hid] = creg[ms * 2 + j];
            }
    }
}

// ---------------------------------------------------------------------------
// fc: out[b,t,n] = sum_hid h[b][n][hid]*fc_w[hid] + fc_b, broadcast over t
// ---------------------------------------------------------------------------
__global__ void fc_kernel(const f16* __restrict__ h, const float* __restrict__ fc_w,
                          const float* __restrict__ fc_b, float* __restrict__ out) {
    int idx = blockIdx.x * 256 + threadIdx.x;      // b*NNP + n
    const half8* hp = (const half8*)(h + (size_t)idx * HID);
    float s = 0.0f;
#pragma unroll
    for (int q = 0; q < 8; ++q) {
        half8 v = hp[q];
#pragma unroll
        for (int e = 0; e < 8; ++e) s += (float)v[e] * fc_w[q * 8 + e];
    }
    s += fc_b[0];
    int b = idx >> 12, n = idx & (NNP - 1);
#pragma unroll
    for (int t = 0; t < TSN; ++t) out[((size_t)b * TSN + t) * NNP + n] = s;
}

extern "C" void kernel_launch(void* const* d_in, const int* in_sizes, int n_in,
                              void* d_out, int out_size, void* d_ws, size_t ws_size,
                              hipStream_t stream) {
    const float* x      = (const float*)d_in[0];
    const float* conv_w = (const float*)d_in[1];
    const float* conv_b = (const float*)d_in[2];
    const float* fc_w   = (const float*)d_in[3];
    const float* fc_b   = (const float*)d_in[4];
    float* out = (float*)d_out;

    char* ws = (char*)d_ws;
    const size_t hbytes = (size_t)BB * NNP * HID * sizeof(f16);     // 8.39 MB
    f16*   wpack  = (f16*)ws;                                       // 112 KiB
    f16*   h_glob = (f16*)(ws + 131072);
    float* c_glob = (float*)(ws + 131072 + hbytes);                 // 16.8 MB

    pack_w_kernel<<<(4 * 64 * KPK + 255) / 256, 256, 0, stream>>>(conv_w, wpack);
    lstm_kernel<<<BB * NTIL, 512, 0, stream>>>(x, wpack, conv_b, h_glob, c_glob, 0);
    lstm_kernel<<<BB * NTIL, 512, 0, stream>>>(x, wpack, conv_b, h_glob, c_glob, 1);
    fc_kernel<<<BB * NNP / 256, 256, 0, stream>>>(h_glob, fc_w, fc_b, out);
}

// Round 11
// 278.737 us; speedup vs baseline: 3.6561x; 1.4184x over previous
//
#include <hip/hip_runtime.h>

typedef _Float16 f16;
typedef __attribute__((ext_vector_type(8))) _Float16 half8;
typedef __attribute__((ext_vector_type(4))) float floatx4;

#define BB    16
#define TSN   16
#define NNP   4096
#define HID   64
#define KPK   224     // 6 k-tiles of 32 (h taps) + 1 k-tile (x taps, 3 live)
#define WOUT  128     // valid output positions per block
#define HALO  8       // time-halo per 8-step chunk (2 launches)
#define WCMP  144     // computed rows per step = WOUT + 2*HALO (9 m-tiles)
#define HROWS 146     // h-buffer rows = WCMP + 2 (conv halo)
#define NMS   9
#define NTIL  32

#define LOG2E 1.44269504088896340736f

// LDS h layout: row stride 64 f16 (128 B == 0 mod 32 banks), 16B chunk
// XOR-swizzled by row (phys_chunk = chunk ^ (row&7)) -> b128 reads balanced,
// dword epilogue writes conflict-light. [verified R5: conflicts 8.3M -> 229K]
__device__ __forceinline__ int hadr(int rr, int c) {   // f16 index
    return rr * 64 + ((c ^ (rr & 7)) << 3);
}
__device__ __forceinline__ unsigned f16pair(float a, float b) {
    union { f16 h; unsigned short u; } ua, ub;
    ua.h = (f16)a; ub.h = (f16)b;
    return (unsigned)ua.u | ((unsigned)ub.u << 16);
}

// Raw-rate transcendentals (no -ffast-math in harness: 1.0f/x lowers to the
// 9-op IEEE divide; __expf carries a base-conversion mul). ~1 ulp each,
// negligible vs the 2.27e-3 absmax budget.
__device__ __forceinline__ float fast_exp2(float x) {
#if __has_builtin(__builtin_amdgcn_exp2f)
    return __builtin_amdgcn_exp2f(x);
#else
    return exp2f(x);
#endif
}
__device__ __forceinline__ float fast_rcp(float x) {
#if __has_builtin(__builtin_amdgcn_rcpf)
    return __builtin_amdgcn_rcpf(x);
#else
    return 1.0f / x;
#endif
}

// ---------------------------------------------------------------------------
// Pack conv_w (OIHW 256x65x3x3, only kw=1 live) -> f16 wpack[oc][k]:
//   k = kt*32+c;  kt<6: tap=kt>>1, ch j=(kt&1)*32+c;  kt=6: c<3 -> x tap c.
// Gate pre-scale folded in: i/f/o by -log2e (sigmoid via exp2), g by 2*log2e
// (tanh via exp2) -> epilogue uses raw v_exp_f32, no per-exp multiplies.
// ---------------------------------------------------------------------------
__global__ void pack_w_kernel(const float* __restrict__ conv_w, f16* __restrict__ wpack) {
    int idx = blockIdx.x * 256 + threadIdx.x;
    if (idx >= 4 * 64 * KPK) return;
    int k  = idx % KPK;
    int oc = idx / KPK;
    int kt = k >> 5, c = k & 31;
    float w = 0.0f;
    if (kt < 6) {
        int tap = kt >> 1;
        int j   = (kt & 1) * 32 + c;
        w = conv_w[((oc * 65 + 1 + j) * 3 + tap) * 3 + 1];
    } else if (c < 3) {
        w = conv_w[((oc * 65 + 0) * 3 + c) * 3 + 1];
    }
    float scale = (oc >= 192) ? (2.0f * LOG2E) : (-LOG2E);
    wpack[oc * KPK + k] = (f16)(w * scale);
}

// ---------------------------------------------------------------------------
// ConvLSTM 8-step chunk, 512 independent blocks, NO inter-block sync.
// Block = 512 thr (8 waves). Gate-packed MFMA N-dim: call q in {0,1} has
// column n -> gate q*2+(n>>3), hid wave*8+(n&7). Per-wave B-frags: 7 kt x 2
// = 56 VGPR.  __launch_bounds__(512,2): allocator lands ~104 VGPR -> no
// spills (R10-verified). Gates arrive PRE-SCALED (see pack) and PRE-BIASED
// (acc initialized to column-constant scaled bias, not zero):
//   sigmoid(x) = rcp(1+exp2(y)),  y = -x*log2e   (gates i,f,o)
//   tanh(x)    = 1-2*rcp(1+exp2(y)), y = 2x*log2e (gate g; tanh(c) scales
//                at runtime: 1 mul)
// Lane pair (m, m+8) holds the two gate-halves of the same (pos,hid);
// gates exchanged via shfl_xor(8); pair splits acc rows (m<8: r=0,1 /
// m>=8: r=2,3). Halo-8 recompute (window 144 rows, shell shrinks 1
// row/step). phase 0: h(0)=c(0)=0, stores h(8),c(8). phase 1: seeds from
// h(8),c(8), stores h(16).
// ---------------------------------------------------------------------------
__global__ __launch_bounds__(512, 2)
void lstm_kernel(const float* __restrict__ x, const f16* __restrict__ wpack,
                 const float* __restrict__ conv_b,
                 f16* __restrict__ h_glob, float* __restrict__ c_glob, int phase)
{
    __shared__ __align__(16) f16 hlds[2][HROWS * 64];
    __shared__ __align__(16) f16 xt[WCMP * 8];

    const int blk  = blockIdx.x;
    const int b    = blk >> 5;
    const int tau  = blk & 31;
    const int n0   = tau * WOUT;
    const int tid  = threadIdx.x;
    const int lane = tid & 63;
    const int wave = tid >> 6;             // 0..7
    const int m    = lane & 15;
    const int kg   = lane >> 4;
    const int gh   = m >> 3;               // gate half of this lane's column
    const int hid  = wave * 8 + (m & 7);
    const bool lowm = (m < 8);
    const bool edge = (tau == 0) || (tau == NTIL - 1);

    // B fragments, gate-packed: bf[kt][q], element k=kg*8+i of column
    // (gate q*2+gh, hid). 14 half8 = 56 VGPR, resident all 8 steps.
    half8 bf[7][2];
#pragma unroll
    for (int kt = 0; kt < 7; ++kt)
#pragma unroll
        for (int q = 0; q < 2; ++q)
            bf[kt][q] = *(const half8*)(wpack + (size_t)((q * 2 + gh) * 64 + hid) * KPK + kt * 32 + kg * 8);

    // scaled bias for this lane's two MFMA columns (acc-init, column-const)
    const float accb0 = conv_b[(0 * 2 + gh) * 64 + hid] * (-LOG2E);
    const float accb1 = conv_b[(1 * 2 + gh) * 64 + hid] * ((gh == 1) ? 2.0f * LOG2E : -LOG2E);

    // c in regs: creg[ms*2+j] <-> pos = n0-HALO + ms*16 + kg*4 + r,
    // r = lowm ? j : 2+j  (lane pair splits the 4 acc rows)
    float creg[NMS * 2];

    if (phase == 0) {
#pragma unroll
        for (int i = 0; i < NMS * 2; ++i) creg[i] = 0.0f;
        for (int i = tid; i < HROWS * 64; i += 512) { hlds[0][i] = (f16)0; hlds[1][i] = (f16)0; }
    } else {
        // seed h(8) window from global (rr <-> pos n0-HALO-1+rr), OOB -> 0
        for (int i = tid; i < HROWS * 8; i += 512) {
            int rr = i >> 3, c = i & 7;
            int pos = n0 - HALO - 1 + rr;
            half8 v = {};
            if (pos >= 0 && pos < NNP)
                v = *(const half8*)(h_glob + ((size_t)b * NNP + pos) * HID + c * 8);
            *(half8*)(hlds[0] + hadr(rr, c)) = v;
        }
        for (int i = tid; i < HROWS * 64; i += 512) hlds[1][i] = (f16)0;
        // seed c(8) for the full window (shell rows read neighbors' valid c)
#pragma unroll
        for (int ms = 0; ms < NMS; ++ms)
#pragma unroll
            for (int j = 0; j < 2; ++j) {
                int r   = lowm ? j : 2 + j;
                int pos = n0 - HALO + ms * 16 + kg * 4 + r;
                creg[ms * 2 + j] = (pos >= 0 && pos < NNP)
                    ? c_glob[((size_t)b * NNP + pos) * HID + hid] : 0.0f;
            }
    }
    for (int i = tid; i < WCMP * 4; i += 512) ((unsigned*)xt)[i] = 0u;
    __syncthreads();

    const int s0 = phase * 8;
#pragma unroll 1
    for (int s = s0; s < s0 + 8; ++s) {
        const f16* hrd = hlds[s & 1];
        f16*       hwr = hlds[(s & 1) ^ 1];

        // stage x(s): xt row r <-> pos p = n0-HALO+r, taps p-1,p,p+1
        if (tid < WCMP) {
            const float* xb = x + ((size_t)b * TSN + s) * NNP;
            int r = tid;
            int p = n0 - HALO + r;
            float v0 = (p - 1 >= 0 && p - 1 < NNP) ? xb[p - 1] : 0.0f;
            float v1 = (p >= 0 && p < NNP) ? xb[p] : 0.0f;
            float v2 = (p + 1 >= 0 && p + 1 < NNP) ? xb[p + 1] : 0.0f;
            ((unsigned*)xt)[r * 4] = f16pair(v0, v1);
            xt[r * 8 + 2] = (f16)v2;
        }
        __syncthreads();   // barrier 1: staging visible; prev-step readers done

#pragma unroll
        for (int ms = 0; ms < NMS; ++ms) {
            const int ar = ms * 16 + m;    // compute-window row of this lane

            floatx4 acc[2];
            acc[0] = (floatx4){accb0, accb0, accb0, accb0};
            acc[1] = (floatx4){accb1, accb1, accb1, accb1};

#pragma unroll
            for (int kt = 0; kt < 6; ++kt) {
                half8 a = *(const half8*)(hrd + hadr(ar + (kt >> 1), (kt & 1) * 4 + kg));
                acc[0] = __builtin_amdgcn_mfma_f32_16x16x32_f16(a, bf[kt][0], acc[0], 0, 0, 0);
                acc[1] = __builtin_amdgcn_mfma_f32_16x16x32_f16(a, bf[kt][1], acc[1], 0, 0, 0);
            }
            {
                // x k-tile: k>=3 weights are 0, so all kg read chunk 0
                half8 a = *(const half8*)(xt + ar * 8);
                acc[0] = __builtin_amdgcn_mfma_f32_16x16x32_f16(a, bf[6][0], acc[0], 0, 0, 0);
                acc[1] = __builtin_amdgcn_mfma_f32_16x16x32_f16(a, bf[6][1], acc[1], 0, 0, 0);
            }

            // gate exchange across the m/m+8 pair; pair splits rows
            float pg[2][2];
#pragma unroll
            for (int q = 0; q < 2; ++q)
#pragma unroll
                for (int j = 0; j < 2; ++j) {
                    float send = lowm ? acc[q][2 + j] : acc[q][j];
                    pg[q][j] = __shfl_xor(send, 8);
                }

#pragma unroll
            for (int j = 0; j < 2; ++j) {
                int r  = lowm ? j : 2 + j;
                // pre-scaled, pre-biased gate values
                float yi = lowm ? acc[0][j] : pg[0][j];
                float yf = lowm ? pg[0][j] : acc[0][2 + j];
                float yo = lowm ? acc[1][j] : pg[1][j];
                float yg = lowm ? pg[1][j] : acc[1][2 + j];
                float si = fast_rcp(1.0f + fast_exp2(yi));
                float sf = fast_rcp(1.0f + fast_exp2(yf));
                float so = fast_rcp(1.0f + fast_exp2(yo));
                float tg = fmaf(-2.0f, fast_rcp(1.0f + fast_exp2(yg)), 1.0f);
                int ridx = ms * 2 + j;
                float cn = fmaf(sf, creg[ridx], si * tg);
                float tc = fmaf(-2.0f, fast_rcp(1.0f + fast_exp2(cn * (2.0f * LOG2E))), 1.0f);
                float hnf = so * tc;
                creg[ridx] = cn;
                int rit = ms * 16 + kg * 4 + r;        // compute-window row
                if (edge) {
                    int pos = n0 - HALO + rit;
                    if (pos < 0 || pos >= NNP) hnf = 0.0f;  // zero-pad semantics
                }
                float po = __shfl_xor(hnf, 1);          // partner hid^1
                if (!(m & 1)) {                          // even lane packs dword
                    int rr = rit + 1;
                    ((unsigned*)hwr)[rr * 32 + ((wave ^ (rr & 7)) << 2) + ((m & 7) >> 1)] =
                        f16pair(hnf, po);
                }
            }
        }
        __syncthreads();   // barrier 2: hwr complete before it becomes hrd
    }

    // h(s0+8) is in hlds[0] (last step is odd); valid rows rr = row+HALO+1.
    for (int i = tid; i < WOUT * 8; i += 512) {
        int row = i >> 3, c = i & 7;
        half8 v = *(const half8*)(hlds[0] + hadr(row + HALO + 1, c));
        *(half8*)(h_glob + ((size_t)b * NNP + n0 + row) * HID + c * 8) = v;
    }
    if (phase == 0) {
        // persist c(8) for valid rows
#pragma unroll
        for (int ms = 0; ms < NMS; ++ms)
#pragma unroll
            for (int j = 0; j < 2; ++j) {
                int r   = lowm ? j : 2 + j;
                int rit = ms * 16 + kg * 4 + r;
                int pos = n0 - HALO + rit;
                if (rit >= HALO && rit < HALO + WOUT && pos >= 0 && pos < NNP)
                    c_glob[((size_t)b * NNP + pos) * HID + hid] = creg[ms * 2 + j];
            }
    }
}

// ---------------------------------------------------------------------------
// fc: out[b,t,n] = sum_hid h[b][n][hid]*fc_w[hid] + fc_b, broadcast over t
// ---------------------------------------------------------------------------
__global__ void fc_kernel(const f16* __restrict__ h, const float* __restrict__ fc_w,
                          const float* __restrict__ fc_b, float* __restrict__ out) {
    int idx = blockIdx.x * 256 + threadIdx.x;      // b*NNP + n
    const half8* hp = (const half8*)(h + (size_t)idx * HID);
    float s = 0.0f;
#pragma unroll
    for (int q = 0; q < 8; ++q) {
        half8 v = hp[q];
#pragma unroll
        for (int e = 0; e < 8; ++e) s += (float)v[e] * fc_w[q * 8 + e];
    }
    s += fc_b[0];
    int b = idx >> 12, n = idx & (NNP - 1);
#pragma unroll
    for (int t = 0; t < TSN; ++t) out[((size_t)b * TSN + t) * NNP + n] = s;
}

extern "C" void kernel_launch(void* const* d_in, const int* in_sizes, int n_in,
                              void* d_out, int out_size, void* d_ws, size_t ws_size,
                              hipStream_t stream) {
    const float* x      = (const float*)d_in[0];
    const float* conv_w = (const float*)d_in[1];
    const float* conv_b = (const float*)d_in[2];
    const float* fc_w   = (const float*)d_in[3];
    const float* fc_b   = (const float*)d_in[4];
    float* out = (float*)d_out;

    char* ws = (char*)d_ws;
    const size_t hbytes = (size_t)BB * NNP * HID * sizeof(f16);     // 8.39 MB
    f16*   wpack  = (f16*)ws;                                       // 112 KiB
    f16*   h_glob = (f16*)(ws + 131072);
    float* c_glob = (float*)(ws + 131072 + hbytes);                 // 16.8 MB

    pack_w_kernel<<<(4 * 64 * KPK + 255) / 256, 256, 0, stream>>>(conv_w, wpack);
    lstm_kernel<<<BB * NTIL, 512, 0, stream>>>(x, wpack, conv_b, h_glob, c_glob, 0);
    lstm_kernel<<<BB * NTIL, 512, 0, stream>>>(x, wpack, conv_b, h_glob, c_glob, 1);
    fc_kernel<<<BB * NNP / 256, 256, 0, stream>>>(h_glob, fc_w, fc_b, out);
}

// Round 12
// 271.880 us; speedup vs baseline: 3.7484x; 1.0252x over previous
//
#include <hip/hip_runtime.h>

typedef _Float16 f16;
typedef __attribute__((ext_vector_type(8))) _Float16 half8;
typedef __attribute__((ext_vector_type(4))) float floatx4;

#define BB    16
#define TSN   16
#define NNP   4096
#define HID   64
#define KPK   224     // 6 k-tiles of 32 (h taps) + 1 k-tile (x taps, 3 live)
#define WOUT  128     // valid output positions per block
#define HALO  8       // time-halo per 8-step chunk (2 launches)
#define WCMP  144     // computed rows per step = WOUT + 2*HALO (9 m-tiles)
#define HROWS 146     // h-buffer rows = WCMP + 2 (conv halo)
#define NMS   9
#define NTIL  32

#define LOG2E 1.44269504088896340736f

// LDS h layout: row stride 64 f16 (128 B == 0 mod 32 banks), 16B chunk
// XOR-swizzled by row (phys_chunk = chunk ^ (row&7)) -> b128 reads balanced,
// dword epilogue writes conflict-light. [verified R5: conflicts 8.3M -> 229K]
__device__ __forceinline__ int hadr(int rr, int c) {   // f16 index
    return rr * 64 + ((c ^ (rr & 7)) << 3);
}
__device__ __forceinline__ unsigned f16pair(float a, float b) {
    union { f16 h; unsigned short u; } ua, ub;
    ua.h = (f16)a; ub.h = (f16)b;
    return (unsigned)ua.u | ((unsigned)ub.u << 16);
}

// Raw-rate transcendentals (no -ffast-math in harness: 1.0f/x lowers to the
// 9-op IEEE divide; __expf carries a base-conversion mul). ~1 ulp each.
__device__ __forceinline__ float fast_exp2(float x) {
#if __has_builtin(__builtin_amdgcn_exp2f)
    return __builtin_amdgcn_exp2f(x);
#else
    return exp2f(x);
#endif
}
__device__ __forceinline__ float fast_rcp(float x) {
#if __has_builtin(__builtin_amdgcn_rcpf)
    return __builtin_amdgcn_rcpf(x);
#else
    return 1.0f / x;
#endif
}

// ---------------------------------------------------------------------------
// Pack conv_w (OIHW 256x65x3x3, only kw=1 live) -> f16 wpack[oc][k]:
//   k = kt*32+c;  kt<6: tap=kt>>1, ch j=(kt&1)*32+c;  kt=6: c<3 -> x tap c.
// Gate pre-scale folded in: i/f/o by -log2e (sigmoid via exp2), g by 2*log2e
// (tanh via exp2) -> epilogue uses raw v_exp_f32, no per-exp multiplies.
// ---------------------------------------------------------------------------
__global__ void pack_w_kernel(const float* __restrict__ conv_w, f16* __restrict__ wpack) {
    int idx = blockIdx.x * 256 + threadIdx.x;
    if (idx >= 4 * 64 * KPK) return;
    int k  = idx % KPK;
    int oc = idx / KPK;
    int kt = k >> 5, c = k & 31;
    float w = 0.0f;
    if (kt < 6) {
        int tap = kt >> 1;
        int j   = (kt & 1) * 32 + c;
        w = conv_w[((oc * 65 + 1 + j) * 3 + tap) * 3 + 1];
    } else if (c < 3) {
        w = conv_w[((oc * 65 + 0) * 3 + c) * 3 + 1];
    }
    float scale = (oc >= 192) ? (2.0f * LOG2E) : (-LOG2E);
    wpack[oc * KPK + k] = (f16)(w * scale);
}

// ---------------------------------------------------------------------------
// ConvLSTM 8-step chunk, 512 independent blocks, NO inter-block sync.
// Block = 512 thr (8 waves). Gate-packed MFMA N-dim: call q in {0,1} has
// column n -> gate q*2+(n>>3), hid wave*8+(n&7). Per-wave B-frags: 7 kt x 2
// = 56 VGPR.  __launch_bounds__(512,2): allocator ~104-120 VGPR, no spills.
// R12 changes vs R11 (attack barrier-lockstep + staging overhead):
//  - ALL 8 steps of x pre-staged into LDS once (xt[8][WCMP][8], 18.4 KB);
//    the per-step staging barrier disappears -> ONE __syncthreads per step
//    (top-of-step: separates step s's reads of buffer P from step s+1's
//    writes to P; the 2-periodic ping-pong makes this sufficient).
//  - ms-tiles processed in PAIRS (MFMAs of both tiles back-to-back, then
//    both epilogues) -> longer independent MFMA runs, 36-update trans batch.
// Gates arrive PRE-SCALED (pack) and PRE-BIASED (acc init = scaled bias):
//   sigmoid(x) = rcp(1+exp2(y)), y = -x*log2e  (i,f,o);  tanh via exp2 (g,c).
// Lane pair (m, m+8) holds the two gate-halves of the same (pos,hid);
// exchange via shfl_xor(8); pair splits acc rows (m<8: r=0,1 / m>=8: 2,3).
// Halo-8 recompute (window 144 rows, shell shrinks 1 row/step). phase 0:
// h(0)=c(0)=0, stores h(8),c(8). phase 1: seeds h(8),c(8), stores h(16).
// ---------------------------------------------------------------------------
__global__ __launch_bounds__(512, 2)
void lstm_kernel(const float* __restrict__ x, const f16* __restrict__ wpack,
                 const float* __restrict__ conv_b,
                 f16* __restrict__ h_glob, float* __restrict__ c_glob, int phase)
{
    __shared__ __align__(16) f16 hlds[2][HROWS * 64];
    __shared__ __align__(16) f16 xt[8 * WCMP * 8];

    const int blk  = blockIdx.x;
    const int b    = blk >> 5;
    const int tau  = blk & 31;
    const int n0   = tau * WOUT;
    const int tid  = threadIdx.x;
    const int lane = tid & 63;
    const int wave = tid >> 6;             // 0..7
    const int m    = lane & 15;
    const int kg   = lane >> 4;
    const int gh   = m >> 3;               // gate half of this lane's column
    const int hid  = wave * 8 + (m & 7);
    const bool lowm = (m < 8);
    const bool edge = (tau == 0) || (tau == NTIL - 1);
    const int s0   = phase * 8;

    // B fragments, gate-packed: bf[kt][q], element k=kg*8+i of column
    // (gate q*2+gh, hid). 14 half8 = 56 VGPR, resident all 8 steps.
    half8 bf[7][2];
#pragma unroll
    for (int kt = 0; kt < 7; ++kt)
#pragma unroll
        for (int q = 0; q < 2; ++q)
            bf[kt][q] = *(const half8*)(wpack + (size_t)((q * 2 + gh) * 64 + hid) * KPK + kt * 32 + kg * 8);

    // scaled bias for this lane's two MFMA columns (acc-init, column-const)
    const float accb0 = conv_b[(0 * 2 + gh) * 64 + hid] * (-LOG2E);
    const float accb1 = conv_b[(1 * 2 + gh) * 64 + hid] * ((gh == 1) ? 2.0f * LOG2E : -LOG2E);

    // c in regs: creg[ms*2+j] <-> pos = n0-HALO + ms*16 + kg*4 + r,
    // r = lowm ? j : 2+j  (lane pair splits the 4 acc rows)
    float creg[NMS * 2];

    // ---- one-time staging: all 8 steps of x (rows also zero cols 3..7) ----
    for (int i = tid; i < 8 * WCMP; i += 512) {
        int ss = i / WCMP, r = i - ss * WCMP;
        const float* xb = x + ((size_t)b * TSN + s0 + ss) * NNP;
        int p = n0 - HALO + r;
        float v0 = (p - 1 >= 0 && p - 1 < NNP) ? xb[p - 1] : 0.0f;
        float v1 = (p >= 0 && p < NNP) ? xb[p] : 0.0f;
        float v2 = (p + 1 >= 0 && p + 1 < NNP) ? xb[p + 1] : 0.0f;
        unsigned* q = (unsigned*)(xt + (size_t)i * 8);
        q[0] = f16pair(v0, v1);
        q[1] = f16pair(v2, 0.0f);
        q[2] = 0u; q[3] = 0u;
    }

    if (phase == 0) {
#pragma unroll
        for (int i = 0; i < NMS * 2; ++i) creg[i] = 0.0f;
        for (int i = tid; i < HROWS * 64; i += 512) { hlds[0][i] = (f16)0; hlds[1][i] = (f16)0; }
    } else {
        // seed h(8) window from global (rr <-> pos n0-HALO-1+rr), OOB -> 0
        for (int i = tid; i < HROWS * 8; i += 512) {
            int rr = i >> 3, c = i & 7;
            int pos = n0 - HALO - 1 + rr;
            half8 v = {};
            if (pos >= 0 && pos < NNP)
                v = *(const half8*)(h_glob + ((size_t)b * NNP + pos) * HID + c * 8);
            *(half8*)(hlds[0] + hadr(rr, c)) = v;
        }
        // hlds[1]: only halo rows 0 / HROWS-1 are read before being written
        for (int i = tid; i < 2 * 64; i += 512) {
            int rr = (i >= 64) ? (HROWS - 1) : 0;
            hlds[1][rr * 64 + (i & 63)] = (f16)0;
        }
        // seed c(8) for the full window (shell rows read neighbors' valid c)
#pragma unroll
        for (int ms = 0; ms < NMS; ++ms)
#pragma unroll
            for (int j = 0; j < 2; ++j) {
                int r   = lowm ? j : 2 + j;
                int pos = n0 - HALO + ms * 16 + kg * 4 + r;
                creg[ms * 2 + j] = (pos >= 0 && pos < NNP)
                    ? c_glob[((size_t)b * NNP + pos) * HID + hid] : 0.0f;
            }
    }

#pragma unroll 1
    for (int s = s0; s < s0 + 8; ++s) {
        __syncthreads();   // step s's reads vs step s-1's writes (and init)
        const f16* hrd = hlds[s & 1];
        f16*       hwr = hlds[(s & 1) ^ 1];
        const f16* xts = xt + (size_t)(s - s0) * WCMP * 8;

        // ms-tiles in pairs: {0,1},{2,3},{4,5},{6,7},{8}
#pragma unroll
        for (int mp = 0; mp < 5; ++mp) {
            const int msA = mp * 2;
            const bool two = (msA + 1 < NMS);

            floatx4 acc[2][2];   // [tile][q]
#pragma unroll
            for (int ti = 0; ti < 2; ++ti) {
                acc[ti][0] = (floatx4){accb0, accb0, accb0, accb0};
                acc[ti][1] = (floatx4){accb1, accb1, accb1, accb1};
            }

#pragma unroll
            for (int ti = 0; ti < 2; ++ti) {
                if (ti == 1 && !two) break;
                const int ar = (msA + ti) * 16 + m;
#pragma unroll
                for (int kt = 0; kt < 6; ++kt) {
                    half8 a = *(const half8*)(hrd + hadr(ar + (kt >> 1), (kt & 1) * 4 + kg));
                    acc[ti][0] = __builtin_amdgcn_mfma_f32_16x16x32_f16(a, bf[kt][0], acc[ti][0], 0, 0, 0);
                    acc[ti][1] = __builtin_amdgcn_mfma_f32_16x16x32_f16(a, bf[kt][1], acc[ti][1], 0, 0, 0);
                }
                {
                    half8 a = *(const half8*)(xts + ar * 8);
                    acc[ti][0] = __builtin_amdgcn_mfma_f32_16x16x32_f16(a, bf[6][0], acc[ti][0], 0, 0, 0);
                    acc[ti][1] = __builtin_amdgcn_mfma_f32_16x16x32_f16(a, bf[6][1], acc[ti][1], 0, 0, 0);
                }
            }

            // batched epilogue for both tiles of the pair
#pragma unroll
            for (int ti = 0; ti < 2; ++ti) {
                if (ti == 1 && !two) break;
                const int ms = msA + ti;

                float pg[2][2];
#pragma unroll
                for (int q = 0; q < 2; ++q)
#pragma unroll
                    for (int j = 0; j < 2; ++j) {
                        float send = lowm ? acc[ti][q][2 + j] : acc[ti][q][j];
                        pg[q][j] = __shfl_xor(send, 8);
                    }

#pragma unroll
                for (int j = 0; j < 2; ++j) {
                    int r  = lowm ? j : 2 + j;
                    float yi = lowm ? acc[ti][0][j] : pg[0][j];
                    float yf = lowm ? pg[0][j] : acc[ti][0][2 + j];
                    float yo = lowm ? acc[ti][1][j] : pg[1][j];
                    float yg = lowm ? pg[1][j] : acc[ti][1][2 + j];
                    float si = fast_rcp(1.0f + fast_exp2(yi));
                    float sf = fast_rcp(1.0f + fast_exp2(yf));
                    float so = fast_rcp(1.0f + fast_exp2(yo));
                    float tg = fmaf(-2.0f, fast_rcp(1.0f + fast_exp2(yg)), 1.0f);
                    int ridx = ms * 2 + j;
                    float cn = fmaf(sf, creg[ridx], si * tg);
                    float tc = fmaf(-2.0f, fast_rcp(1.0f + fast_exp2(cn * (2.0f * LOG2E))), 1.0f);
                    float hnf = so * tc;
                    creg[ridx] = cn;
                    int rit = ms * 16 + kg * 4 + r;        // compute-window row
                    if (edge) {
                        int pos = n0 - HALO + rit;
                        if (pos < 0 || pos >= NNP) hnf = 0.0f;  // zero-pad
                    }
                    float po = __shfl_xor(hnf, 1);          // partner hid^1
                    if (!(m & 1)) {                          // even lane packs dword
                        int rr = rit + 1;
                        ((unsigned*)hwr)[rr * 32 + ((wave ^ (rr & 7)) << 2) + ((m & 7) >> 1)] =
                            f16pair(hnf, po);
                    }
                }
            }
        }
    }
    __syncthreads();   // last step's hwr (= hlds[0]) complete

    // h(s0+8) is in hlds[0] (last step is odd); valid rows rr = row+HALO+1.
    for (int i = tid; i < WOUT * 8; i += 512) {
        int row = i >> 3, c = i & 7;
        half8 v = *(const half8*)(hlds[0] + hadr(row + HALO + 1, c));
        *(half8*)(h_glob + ((size_t)b * NNP + n0 + row) * HID + c * 8) = v;
    }
    if (phase == 0) {
        // persist c(8) for valid rows
#pragma unroll
        for (int ms = 0; ms < NMS; ++ms)
#pragma unroll
            for (int j = 0; j < 2; ++j) {
                int r   = lowm ? j : 2 + j;
                int rit = ms * 16 + kg * 4 + r;
                int pos = n0 - HALO + rit;
                if (rit >= HALO && rit < HALO + WOUT && pos >= 0 && pos < NNP)
                    c_glob[((size_t)b * NNP + pos) * HID + hid] = creg[ms * 2 + j];
            }
    }
}

// ---------------------------------------------------------------------------
// fc: out[b,t,n] = sum_hid h[b][n][hid]*fc_w[hid] + fc_b, broadcast over t
// ---------------------------------------------------------------------------
__global__ void fc_kernel(const f16* __restrict__ h, const float* __restrict__ fc_w,
                          const float* __restrict__ fc_b, float* __restrict__ out) {
    int idx = blockIdx.x * 256 + threadIdx.x;      // b*NNP + n
    const half8* hp = (const half8*)(h + (size_t)idx * HID);
    float s = 0.0f;
#pragma unroll
    for (int q = 0; q < 8; ++q) {
        half8 v = hp[q];
#pragma unroll
        for (int e = 0; e < 8; ++e) s += (float)v[e] * fc_w[q * 8 + e];
    }
    s += fc_b[0];
    int b = idx >> 12, n = idx & (NNP - 1);
#pragma unroll
    for (int t = 0; t < TSN; ++t) out[((size_t)b * TSN + t) * NNP + n] = s;
}

extern "C" void kernel_launch(void* const* d_in, const int* in_sizes, int n_in,
                              void* d_out, int out_size, void* d_ws, size_t ws_size,
                              hipStream_t stream) {
    const float* x      = (const float*)d_in[0];
    const float* conv_w = (const float*)d_in[1];
    const float* conv_b = (const float*)d_in[2];
    const float* fc_w   = (const float*)d_in[3];
    const float* fc_b   = (const float*)d_in[4];
    float* out = (float*)d_out;

    char* ws = (char*)d_ws;
    const size_t hbytes = (size_t)BB * NNP * HID * sizeof(f16);     // 8.39 MB
    f16*   wpack  = (f16*)ws;                                       // 112 KiB
    f16*   h_glob = (f16*)(ws + 131072);
    float* c_glob = (float*)(ws + 131072 + hbytes);                 // 16.8 MB

    pack_w_kernel<<<(4 * 64 * KPK + 255) / 256, 256, 0, stream>>>(conv_w, wpack);
    lstm_kernel<<<BB * NTIL, 512, 0, stream>>>(x, wpack, conv_b, h_glob, c_glob, 0);
    lstm_kernel<<<BB * NTIL, 512, 0, stream>>>(x, wpack, conv_b, h_glob, c_glob, 1);
    fc_kernel<<<BB * NNP / 256, 256, 0, stream>>>(h_glob, fc_w, fc_b, out);
}

// Round 13
// 266.591 us; speedup vs baseline: 3.8227x; 1.0198x over previous
//
#include <hip/hip_runtime.h>

typedef _Float16 f16;
typedef __attribute__((ext_vector_type(8))) _Float16 half8;
typedef __attribute__((ext_vector_type(4))) float floatx4;

#define BB    16
#define TSN   16
#define NNP   4096
#define HID   64
#define KPK   224     // 6 k-tiles of 32 (h taps) + 1 k-tile (x taps, 3 live)
#define WOUT  128     // valid output positions per block
#define HALO  8       // time-halo per 8-step chunk (2 launches)
#define WCMP  144     // computed rows per step = WOUT + 2*HALO (9 m-tiles)
#define HROWS 146     // h-buffer rows = WCMP + 2 (conv halo)
#define NMS   9
#define NTIL  32

#define LOG2E 1.44269504088896340736f

// LDS h layout: row stride 64 f16 (128 B == 0 mod 32 banks), 16B chunk
// XOR-swizzled by row (phys_chunk = chunk ^ (row&7)) -> b128 reads balanced,
// dword epilogue writes conflict-light. [verified R5: conflicts 8.3M -> 229K]
__device__ __forceinline__ int hadr(int rr, int c) {   // f16 index
    return rr * 64 + ((c ^ (rr & 7)) << 3);
}
__device__ __forceinline__ unsigned f16pair(float a, float b) {
    union { f16 h; unsigned short u; } ua, ub;
    ua.h = (f16)a; ub.h = (f16)b;
    return (unsigned)ua.u | ((unsigned)ub.u << 16);
}

// Raw-rate transcendentals (no -ffast-math in harness: 1.0f/x lowers to the
// 9-op IEEE divide; __expf carries a base-conversion mul). ~1 ulp each.
__device__ __forceinline__ float fast_exp2(float x) {
#if __has_builtin(__builtin_amdgcn_exp2f)
    return __builtin_amdgcn_exp2f(x);
#else
    return exp2f(x);
#endif
}
__device__ __forceinline__ float fast_rcp(float x) {
#if __has_builtin(__builtin_amdgcn_rcpf)
    return __builtin_amdgcn_rcpf(x);
#else
    return 1.0f / x;
#endif
}

// Lane exchanges via DPP (VALU, 2 cyc) instead of __shfl_xor (ds_swizzle on
// the DS pipe, ~5.8 cyc — R12 had ~6912 of them competing with A-frag reads).
// xor-8 within 16-lane rows == row_ror:8 (0x128); xor-1 == quad_perm
// [1,0,3,2] (0xB1). All source lanes active -> bound_ctrl irrelevant.
__device__ __forceinline__ float dpp_xor8(float v) {
    return __int_as_float(__builtin_amdgcn_mov_dpp(__float_as_int(v), 0x128, 0xF, 0xF, true));
}
__device__ __forceinline__ float dpp_xor1(float v) {
    return __int_as_float(__builtin_amdgcn_mov_dpp(__float_as_int(v), 0xB1, 0xF, 0xF, true));
}

// ---------------------------------------------------------------------------
// Pack conv_w (OIHW 256x65x3x3, only kw=1 live) -> f16 wpack[oc][k]:
//   k = kt*32+c;  kt<6: tap=kt>>1, ch j=(kt&1)*32+c;  kt=6: c<3 -> x tap c.
// Gate pre-scale folded in: i/f/o by -log2e (sigmoid via exp2), g by 2*log2e
// (tanh via exp2) -> epilogue uses raw v_exp_f32, no per-exp multiplies.
// ---------------------------------------------------------------------------
__global__ void pack_w_kernel(const float* __restrict__ conv_w, f16* __restrict__ wpack) {
    int idx = blockIdx.x * 256 + threadIdx.x;
    if (idx >= 4 * 64 * KPK) return;
    int k  = idx % KPK;
    int oc = idx / KPK;
    int kt = k >> 5, c = k & 31;
    float w = 0.0f;
    if (kt < 6) {
        int tap = kt >> 1;
        int j   = (kt & 1) * 32 + c;
        w = conv_w[((oc * 65 + 1 + j) * 3 + tap) * 3 + 1];
    } else if (c < 3) {
        w = conv_w[((oc * 65 + 0) * 3 + c) * 3 + 1];
    }
    float scale = (oc >= 192) ? (2.0f * LOG2E) : (-LOG2E);
    wpack[oc * KPK + k] = (f16)(w * scale);
}

// ---------------------------------------------------------------------------
// One ms-tile-pair: MFMAs for tiles {MSA, MSA+1} back-to-back, then both
// epilogues. Template params keep creg indices compile-time (register array).
// ---------------------------------------------------------------------------
template <int MSA, bool TWO>
__device__ __forceinline__ void do_pair(
    const f16* __restrict__ hrd, f16* __restrict__ hwr,
    const f16* __restrict__ xts, const half8 (&bf)[7][2],
    float accb0, float accb1, float (&creg)[NMS * 2],
    int m, int kg, int wave, bool lowm, bool edge, int n0)
{
    floatx4 acc[2][2];   // [tile][q]
#pragma unroll
    for (int ti = 0; ti < 2; ++ti) {
        acc[ti][0] = (floatx4){accb0, accb0, accb0, accb0};
        acc[ti][1] = (floatx4){accb1, accb1, accb1, accb1};
    }

#pragma unroll
    for (int ti = 0; ti < 2; ++ti) {
        if (ti == 1 && !TWO) break;
        const int ar = (MSA + ti) * 16 + m;
#pragma unroll
        for (int kt = 0; kt < 6; ++kt) {
            half8 a = *(const half8*)(hrd + hadr(ar + (kt >> 1), (kt & 1) * 4 + kg));
            acc[ti][0] = __builtin_amdgcn_mfma_f32_16x16x32_f16(a, bf[kt][0], acc[ti][0], 0, 0, 0);
            acc[ti][1] = __builtin_amdgcn_mfma_f32_16x16x32_f16(a, bf[kt][1], acc[ti][1], 0, 0, 0);
        }
        {
            half8 a = *(const half8*)(xts + ar * 8);
            acc[ti][0] = __builtin_amdgcn_mfma_f32_16x16x32_f16(a, bf[6][0], acc[ti][0], 0, 0, 0);
            acc[ti][1] = __builtin_amdgcn_mfma_f32_16x16x32_f16(a, bf[6][1], acc[ti][1], 0, 0, 0);
        }
    }

#pragma unroll
    for (int ti = 0; ti < 2; ++ti) {
        if (ti == 1 && !TWO) break;
        const int ms = MSA + ti;

        float pg[2][2];
#pragma unroll
        for (int q = 0; q < 2; ++q)
#pragma unroll
            for (int j = 0; j < 2; ++j) {
                float send = lowm ? acc[ti][q][2 + j] : acc[ti][q][j];
                pg[q][j] = dpp_xor8(send);
            }

#pragma unroll
        for (int j = 0; j < 2; ++j) {
            int r  = lowm ? j : 2 + j;
            float yi = lowm ? acc[ti][0][j] : pg[0][j];
            float yf = lowm ? pg[0][j] : acc[ti][0][2 + j];
            float yo = lowm ? acc[ti][1][j] : pg[1][j];
            float yg = lowm ? pg[1][j] : acc[ti][1][2 + j];
            float si = fast_rcp(1.0f + fast_exp2(yi));
            float sf = fast_rcp(1.0f + fast_exp2(yf));
            float so = fast_rcp(1.0f + fast_exp2(yo));
            float tg = fmaf(-2.0f, fast_rcp(1.0f + fast_exp2(yg)), 1.0f);
            int ridx = ms * 2 + j;
            float cn = fmaf(sf, creg[ridx], si * tg);
            float tc = fmaf(-2.0f, fast_rcp(1.0f + fast_exp2(cn * (2.0f * LOG2E))), 1.0f);
            float hnf = so * tc;
            creg[ridx] = cn;
            int rit = ms * 16 + kg * 4 + r;        // compute-window row
            if (edge) {
                int pos = n0 - HALO + rit;
                if (pos < 0 || pos >= NNP) hnf = 0.0f;  // zero-pad
            }
            float po = dpp_xor1(hnf);               // partner hid^1
            if (!(m & 1)) {                          // even lane packs dword
                int rr = rit + 1;
                ((unsigned*)hwr)[rr * 32 + ((wave ^ (rr & 7)) << 2) + ((m & 7) >> 1)] =
                    f16pair(hnf, po);
            }
        }
    }
}

// ---------------------------------------------------------------------------
// ConvLSTM 8-step chunk, 512 independent blocks, NO inter-block sync.
// Block = 512 thr (8 waves). Gate-packed MFMA N-dim: call q in {0,1} has
// column n -> gate q*2+(n>>3), hid wave*8+(n&7). Per-wave B-frags: 7 kt x 2
// = 56 VGPR.  __launch_bounds__(512,2): allocator ~104-120 VGPR, no spills.
// R13: (a) DPP lane exchange (off the DS pipe); (b) wave-group stagger —
// waves 0-3 process tile-pairs (0,2,4,6,8), waves 4-7 (4,6,8,0,2); wave w
// and w+4 share a SIMD, so each SIMD interleaves one DS/MFMA-phase wave
// with one VALU/epilogue-phase wave between the per-step barriers.
// All 8 steps of x pre-staged once (xt 18.4 KB); ONE barrier per step.
// Gates PRE-SCALED (pack) and PRE-BIASED (acc init = scaled bias).
// Halo-8 recompute. phase 0: h(0)=c(0)=0 -> h(8),c(8); phase 1 -> h(16).
// ---------------------------------------------------------------------------
__global__ __launch_bounds__(512, 2)
void lstm_kernel(const float* __restrict__ x, const f16* __restrict__ wpack,
                 const float* __restrict__ conv_b,
                 f16* __restrict__ h_glob, float* __restrict__ c_glob, int phase)
{
    __shared__ __align__(16) f16 hlds[2][HROWS * 64];
    __shared__ __align__(16) f16 xt[8 * WCMP * 8];

    const int blk  = blockIdx.x;
    const int b    = blk >> 5;
    const int tau  = blk & 31;
    const int n0   = tau * WOUT;
    const int tid  = threadIdx.x;
    const int lane = tid & 63;
    const int wave = tid >> 6;             // 0..7
    const int m    = lane & 15;
    const int kg   = lane >> 4;
    const int gh   = m >> 3;               // gate half of this lane's column
    const int hid  = wave * 8 + (m & 7);
    const bool lowm = (m < 8);
    const bool edge = (tau == 0) || (tau == NTIL - 1);
    const int s0   = phase * 8;

    // B fragments, gate-packed: bf[kt][q], element k=kg*8+i of column
    // (gate q*2+gh, hid). 14 half8 = 56 VGPR, resident all 8 steps.
    half8 bf[7][2];
#pragma unroll
    for (int kt = 0; kt < 7; ++kt)
#pragma unroll
        for (int q = 0; q < 2; ++q)
            bf[kt][q] = *(const half8*)(wpack + (size_t)((q * 2 + gh) * 64 + hid) * KPK + kt * 32 + kg * 8);

    // scaled bias for this lane's two MFMA columns (acc-init, column-const)
    const float accb0 = conv_b[(0 * 2 + gh) * 64 + hid] * (-LOG2E);
    const float accb1 = conv_b[(1 * 2 + gh) * 64 + hid] * ((gh == 1) ? 2.0f * LOG2E : -LOG2E);

    // c in regs: creg[ms*2+j] <-> pos = n0-HALO + ms*16 + kg*4 + r,
    // r = lowm ? j : 2+j  (lane pair splits the 4 acc rows)
    float creg[NMS * 2];

    // ---- one-time staging: all 8 steps of x (rows also zero cols 3..7) ----
    for (int i = tid; i < 8 * WCMP; i += 512) {
        int ss = i / WCMP, r = i - ss * WCMP;
        const float* xb = x + ((size_t)b * TSN + s0 + ss) * NNP;
        int p = n0 - HALO + r;
        float v0 = (p - 1 >= 0 && p - 1 < NNP) ? xb[p - 1] : 0.0f;
        float v1 = (p >= 0 && p < NNP) ? xb[p] : 0.0f;
        float v2 = (p + 1 >= 0 && p + 1 < NNP) ? xb[p + 1] : 0.0f;
        unsigned* q = (unsigned*)(xt + (size_t)i * 8);
        q[0] = f16pair(v0, v1);
        q[1] = f16pair(v2, 0.0f);
        q[2] = 0u; q[3] = 0u;
    }

    if (phase == 0) {
#pragma unroll
        for (int i = 0; i < NMS * 2; ++i) creg[i] = 0.0f;
        for (int i = tid; i < HROWS * 64; i += 512) { hlds[0][i] = (f16)0; hlds[1][i] = (f16)0; }
    } else {
        // seed h(8) window from global (rr <-> pos n0-HALO-1+rr), OOB -> 0
        for (int i = tid; i < HROWS * 8; i += 512) {
            int rr = i >> 3, c = i & 7;
            int pos = n0 - HALO - 1 + rr;
            half8 v = {};
            if (pos >= 0 && pos < NNP)
                v = *(const half8*)(h_glob + ((size_t)b * NNP + pos) * HID + c * 8);
            *(half8*)(hlds[0] + hadr(rr, c)) = v;
        }
        // hlds[1]: only halo rows 0 / HROWS-1 are read before being written
        for (int i = tid; i < 2 * 64; i += 512) {
            int rr = (i >= 64) ? (HROWS - 1) : 0;
            hlds[1][rr * 64 + (i & 63)] = (f16)0;
        }
        // seed c(8) for the full window (shell rows read neighbors' valid c)
#pragma unroll
        for (int ms = 0; ms < NMS; ++ms)
#pragma unroll
            for (int j = 0; j < 2; ++j) {
                int r   = lowm ? j : 2 + j;
                int pos = n0 - HALO + ms * 16 + kg * 4 + r;
                creg[ms * 2 + j] = (pos >= 0 && pos < NNP)
                    ? c_glob[((size_t)b * NNP + pos) * HID + hid] : 0.0f;
            }
    }

#pragma unroll 1
    for (int s = s0; s < s0 + 8; ++s) {
        __syncthreads();   // step s's reads vs step s-1's writes (and init)
        const f16* hrd = hlds[s & 1];
        f16*       hwr = hlds[(s & 1) ^ 1];
        const f16* xts = xt + (size_t)(s - s0) * WCMP * 8;

        if (wave < 4) {
            do_pair<0, true >(hrd, hwr, xts, bf, accb0, accb1, creg, m, kg, wave, lowm, edge, n0);
            do_pair<2, true >(hrd, hwr, xts, bf, accb0, accb1, creg, m, kg, wave, lowm, edge, n0);
            do_pair<4, true >(hrd, hwr, xts, bf, accb0, accb1, creg, m, kg, wave, lowm, edge, n0);
            do_pair<6, true >(hrd, hwr, xts, bf, accb0, accb1, creg, m, kg, wave, lowm, edge, n0);
            do_pair<8, false>(hrd, hwr, xts, bf, accb0, accb1, creg, m, kg, wave, lowm, edge, n0);
        } else {
            do_pair<4, true >(hrd, hwr, xts, bf, accb0, accb1, creg, m, kg, wave, lowm, edge, n0);
            do_pair<6, true >(hrd, hwr, xts, bf, accb0, accb1, creg, m, kg, wave, lowm, edge, n0);
            do_pair<8, false>(hrd, hwr, xts, bf, accb0, accb1, creg, m, kg, wave, lowm, edge, n0);
            do_pair<0, true >(hrd, hwr, xts, bf, accb0, accb1, creg, m, kg, wave, lowm, edge, n0);
            do_pair<2, true >(hrd, hwr, xts, bf, accb0, accb1, creg, m, kg, wave, lowm, edge, n0);
        }
    }
    __syncthreads();   // last step's hwr (= hlds[0]) complete

    // h(s0+8) is in hlds[0] (last step is odd); valid rows rr = row+HALO+1.
    for (int i = tid; i < WOUT * 8; i += 512) {
        int row = i >> 3, c = i & 7;
        half8 v = *(const half8*)(hlds[0] + hadr(row + HALO + 1, c));
        *(half8*)(h_glob + ((size_t)b * NNP + n0 + row) * HID + c * 8) = v;
    }
    if (phase == 0) {
        // persist c(8) for valid rows
#pragma unroll
        for (int ms = 0; ms < NMS; ++ms)
#pragma unroll
            for (int j = 0; j < 2; ++j) {
                int r   = lowm ? j : 2 + j;
                int rit = ms * 16 + kg * 4 + r;
                int pos = n0 - HALO + rit;
                if (rit >= HALO && rit < HALO + WOUT && pos >= 0 && pos < NNP)
                    c_glob[((size_t)b * NNP + pos) * HID + hid] = creg[ms * 2 + j];
            }
    }
}

// ---------------------------------------------------------------------------
// fc: out[b,t,n] = sum_hid h[b][n][hid]*fc_w[hid] + fc_b, broadcast over t
// ---------------------------------------------------------------------------
__global__ void fc_kernel(const f16* __restrict__ h, const float* __restrict__ fc_w,
                          const float* __restrict__ fc_b, float* __restrict__ out) {
    int idx = blockIdx.x * 256 + threadIdx.x;      // b*NNP + n
    const half8* hp = (const half8*)(h + (size_t)idx * HID);
    float s = 0.0f;
#pragma unroll
    for (int q = 0; q < 8; ++q) {
        half8 v = hp[q];
#pragma unroll
        for (int e = 0; e < 8; ++e) s += (float)v[e] * fc_w[q * 8 + e];
    }
    s += fc_b[0];
    int b = idx >> 12, n = idx & (NNP - 1);
#pragma unroll
    for (int t = 0; t < TSN; ++t) out[((size_t)b * TSN + t) * NNP + n] = s;
}

extern "C" void kernel_launch(void* const* d_in, const int* in_sizes, int n_in,
                              void* d_out, int out_size, void* d_ws, size_t ws_size,
                              hipStream_t stream) {
    const float* x      = (const float*)d_in[0];
    const float* conv_w = (const float*)d_in[1];
    const float* conv_b = (const float*)d_in[2];
    const float* fc_w   = (const float*)d_in[3];
    const float* fc_b   = (const float*)d_in[4];
    float* out = (float*)d_out;

    char* ws = (char*)d_ws;
    const size_t hbytes = (size_t)BB * NNP * HID * sizeof(f16);     // 8.39 MB
    f16*   wpack  = (f16*)ws;                                       // 112 KiB
    f16*   h_glob = (f16*)(ws + 131072);
    float* c_glob = (float*)(ws + 131072 + hbytes);                 // 16.8 MB

    pack_w_kernel<<<(4 * 64 * KPK + 255) / 256, 256, 0, stream>>>(conv_w, wpack);
    lstm_kernel<<<BB * NTIL, 512, 0, stream>>>(x, wpack, conv_b, h_glob, c_glob, 0);
    lstm_kernel<<<BB * NTIL, 512, 0, stream>>>(x, wpack, conv_b, h_glob, c_glob, 1);
    fc_kernel<<<BB * NNP / 256, 256, 0, stream>>>(h_glob, fc_w, fc_b, out);
}

// Round 15
// 257.149 us; speedup vs baseline: 3.9631x; 1.0367x over previous
//
#include <hip/hip_runtime.h>

typedef _Float16 f16;
typedef __attribute__((ext_vector_type(8))) _Float16 half8;
typedef __attribute__((ext_vector_type(4))) float floatx4;

#define BB    16
#define TSN   16
#define NNP   4096
#define HID   64
#define KPK   224     // 6 k-tiles of 32 (h taps) + 1 k-tile (x taps, 3 live)
#define WOUT  128     // valid output positions per block
#define HALO  8       // time-halo per 8-step chunk (2 launches)
#define WCMP  144     // computed rows per step = WOUT + 2*HALO (9 m-tiles)
#define HROWS 146     // h-buffer rows = WCMP + 2 (conv halo)
#define NMS   9
#define NTIL  32

#define LOG2E 1.44269504088896340736f

// LDS h layout: row stride 64 f16 (128 B == 0 mod 32 banks), 16B chunk
// XOR-swizzled by row (phys_chunk = chunk ^ (row&7)) -> b128 reads balanced,
// dword epilogue writes conflict-light. [verified R5: conflicts 8.3M -> 229K]
__device__ __forceinline__ int hadr(int rr, int c) {   // f16 index
    return rr * 64 + ((c ^ (rr & 7)) << 3);
}
__device__ __forceinline__ unsigned f16pair(float a, float b) {
    union { f16 h; unsigned short u; } ua, ub;
    ua.h = (f16)a; ub.h = (f16)b;
    return (unsigned)ua.u | ((unsigned)ub.u << 16);
}
// one-instruction f32x2 -> f16x2 pack (v_cvt_pkrtz_f16_f32).
// NOTE: builtin returns __fp16-vector, not _Float16-vector (R14 compile fix).
__device__ __forceinline__ unsigned pkrtz(float a, float b) {
    typedef __fp16 h2v __attribute__((ext_vector_type(2)));
    h2v r = __builtin_amdgcn_cvt_pkrtz(a, b);
    union { h2v h; unsigned u; } cv; cv.h = r; return cv.u;
}

// Raw-rate transcendentals (no -ffast-math in harness). ~1 ulp each.
__device__ __forceinline__ float fast_exp2(float x) {
#if __has_builtin(__builtin_amdgcn_exp2f)
    return __builtin_amdgcn_exp2f(x);
#else
    return exp2f(x);
#endif
}
__device__ __forceinline__ float fast_rcp(float x) {
#if __has_builtin(__builtin_amdgcn_rcpf)
    return __builtin_amdgcn_rcpf(x);
#else
    return 1.0f / x;
#endif
}

// Lane exchanges via DPP (VALU) instead of ds_swizzle (DS pipe).
__device__ __forceinline__ float dpp_xor8(float v) {
    return __int_as_float(__builtin_amdgcn_mov_dpp(__float_as_int(v), 0x128, 0xF, 0xF, true));
}
__device__ __forceinline__ float dpp_xor1(float v) {
    return __int_as_float(__builtin_amdgcn_mov_dpp(__float_as_int(v), 0xB1, 0xF, 0xF, true));
}

// ---------------------------------------------------------------------------
// Pack conv_w (OIHW 256x65x3x3, only kw=1 live) -> f16 wpack[oc][k]:
//   k = kt*32+c;  kt<6: tap=kt>>1, ch j=(kt&1)*32+c;  kt=6: c<3 -> x tap c.
// Gate pre-scale folded in: i/f/o by -log2e, g by 2*log2e.
// ---------------------------------------------------------------------------
__global__ void pack_w_kernel(const float* __restrict__ conv_w, f16* __restrict__ wpack) {
    int idx = blockIdx.x * 256 + threadIdx.x;
    if (idx >= 4 * 64 * KPK) return;
    int k  = idx % KPK;
    int oc = idx / KPK;
    int kt = k >> 5, c = k & 31;
    float w = 0.0f;
    if (kt < 6) {
        int tap = kt >> 1;
        int j   = (kt & 1) * 32 + c;
        w = conv_w[((oc * 65 + 1 + j) * 3 + tap) * 3 + 1];
    } else if (c < 3) {
        w = conv_w[((oc * 65 + 0) * 3 + c) * 3 + 1];
    }
    float scale = (oc >= 192) ? (2.0f * LOG2E) : (-LOG2E);
    wpack[oc * KPK + k] = (f16)(w * scale);
}

// ---------------------------------------------------------------------------
// Single-tile MFMA block: fills one acc set (bias-init). Template keeps all
// indexing compile-time.
// ---------------------------------------------------------------------------
template <int MS>
__device__ __forceinline__ void do_mfma(
    const f16* __restrict__ hrd, const f16* __restrict__ xts,
    const half8 (&bf)[7][2], float accb0, float accb1,
    floatx4 (&acc)[2], int m, int kg)
{
    acc[0] = (floatx4){accb0, accb0, accb0, accb0};
    acc[1] = (floatx4){accb1, accb1, accb1, accb1};
    const int ar = MS * 16 + m;
#pragma unroll
    for (int kt = 0; kt < 6; ++kt) {
        half8 a = *(const half8*)(hrd + hadr(ar + (kt >> 1), (kt & 1) * 4 + kg));
        acc[0] = __builtin_amdgcn_mfma_f32_16x16x32_f16(a, bf[kt][0], acc[0], 0, 0, 0);
        acc[1] = __builtin_amdgcn_mfma_f32_16x16x32_f16(a, bf[kt][1], acc[1], 0, 0, 0);
    }
    {
        half8 a = *(const half8*)(xts + ar * 8);
        acc[0] = __builtin_amdgcn_mfma_f32_16x16x32_f16(a, bf[6][0], acc[0], 0, 0, 0);
        acc[1] = __builtin_amdgcn_mfma_f32_16x16x32_f16(a, bf[6][1], acc[1], 0, 0, 0);
    }
}

// ---------------------------------------------------------------------------
// Single-tile epilogue: gate exchange (DPP), LSTM pointwise, h write.
// ---------------------------------------------------------------------------
template <int MS>
__device__ __forceinline__ void do_epi(
    f16* __restrict__ hwr, floatx4 (&acc)[2], float (&creg)[NMS * 2],
    int m, int kg, int wave, bool lowm, bool edge, int n0)
{
    float pg[2][2];
#pragma unroll
    for (int q = 0; q < 2; ++q)
#pragma unroll
        for (int j = 0; j < 2; ++j) {
            float send = lowm ? acc[q][2 + j] : acc[q][j];
            pg[q][j] = dpp_xor8(send);
        }

#pragma unroll
    for (int j = 0; j < 2; ++j) {
        int r  = lowm ? j : 2 + j;
        float yi = lowm ? acc[0][j] : pg[0][j];
        float yf = lowm ? pg[0][j] : acc[0][2 + j];
        float yo = lowm ? acc[1][j] : pg[1][j];
        float yg = lowm ? pg[1][j] : acc[1][2 + j];
        float si = fast_rcp(1.0f + fast_exp2(yi));
        float sf = fast_rcp(1.0f + fast_exp2(yf));
        float so = fast_rcp(1.0f + fast_exp2(yo));
        float tg = fmaf(-2.0f, fast_rcp(1.0f + fast_exp2(yg)), 1.0f);
        const int ridx = MS * 2 + j;
        float cn = fmaf(sf, creg[ridx], si * tg);
        float tc = fmaf(-2.0f, fast_rcp(1.0f + fast_exp2(cn * (2.0f * LOG2E))), 1.0f);
        float hnf = so * tc;
        creg[ridx] = cn;
        int rit = MS * 16 + kg * 4 + r;        // compute-window row
        if (edge) {
            int pos = n0 - HALO + rit;
            if (pos < 0 || pos >= NNP) hnf = 0.0f;  // zero-pad semantics
        }
        float po = dpp_xor1(hnf);               // partner hid^1
        if (!(m & 1)) {                          // even lane packs dword
            int rr = rit + 1;
            ((unsigned*)hwr)[rr * 32 + ((wave ^ (rr & 7)) << 2) + ((m & 7) >> 1)] =
                pkrtz(hnf, po);
        }
    }
}

// ---------------------------------------------------------------------------
// ConvLSTM 8-step chunk, 512 independent blocks, NO inter-block sync.
// Block = 512 thr (8 waves). Gate-packed MFMA N-dim (R9); DPP exchange (R13);
// all 8 x-steps pre-staged, ONE barrier/step (R12); halo-8 recompute (R9).
// R14: SOFTWARE PIPELINE — ping-pong acc sets so tile t+1's ds_read+MFMA
// issue during tile t's epilogue trans chains (the R13 post-mortem showed
// no pipe >35% busy: wall is dependency latency, not throughput). Wave
// groups stagger start tile (0 vs 4) to spread DS pressure.
// ---------------------------------------------------------------------------
__global__ __launch_bounds__(512, 2)
void lstm_kernel(const float* __restrict__ x, const f16* __restrict__ wpack,
                 const float* __restrict__ conv_b,
                 f16* __restrict__ h_glob, float* __restrict__ c_glob, int phase)
{
    __shared__ __align__(16) f16 hlds[2][HROWS * 64];
    __shared__ __align__(16) f16 xt[8 * WCMP * 8];

    const int blk  = blockIdx.x;
    const int b    = blk >> 5;
    const int tau  = blk & 31;
    const int n0   = tau * WOUT;
    const int tid  = threadIdx.x;
    const int lane = tid & 63;
    const int wave = tid >> 6;             // 0..7
    const int m    = lane & 15;
    const int kg   = lane >> 4;
    const int gh   = m >> 3;               // gate half of this lane's column
    const int hid  = wave * 8 + (m & 7);
    const bool lowm = (m < 8);
    const bool edge = (tau == 0) || (tau == NTIL - 1);
    const int s0   = phase * 8;

    // B fragments, gate-packed: 14 half8 = 56 VGPR, resident all 8 steps.
    half8 bf[7][2];
#pragma unroll
    for (int kt = 0; kt < 7; ++kt)
#pragma unroll
        for (int q = 0; q < 2; ++q)
            bf[kt][q] = *(const half8*)(wpack + (size_t)((q * 2 + gh) * 64 + hid) * KPK + kt * 32 + kg * 8);

    const float accb0 = conv_b[(0 * 2 + gh) * 64 + hid] * (-LOG2E);
    const float accb1 = conv_b[(1 * 2 + gh) * 64 + hid] * ((gh == 1) ? 2.0f * LOG2E : -LOG2E);

    float creg[NMS * 2];

    // ---- one-time staging: all 8 steps of x ----
    for (int i = tid; i < 8 * WCMP; i += 512) {
        int ss = i / WCMP, r = i - ss * WCMP;
        const float* xb = x + ((size_t)b * TSN + s0 + ss) * NNP;
        int p = n0 - HALO + r;
        float v0 = (p - 1 >= 0 && p - 1 < NNP) ? xb[p - 1] : 0.0f;
        float v1 = (p >= 0 && p < NNP) ? xb[p] : 0.0f;
        float v2 = (p + 1 >= 0 && p + 1 < NNP) ? xb[p + 1] : 0.0f;
        unsigned* q = (unsigned*)(xt + (size_t)i * 8);
        q[0] = f16pair(v0, v1);
        q[1] = f16pair(v2, 0.0f);
        q[2] = 0u; q[3] = 0u;
    }

    if (phase == 0) {
#pragma unroll
        for (int i = 0; i < NMS * 2; ++i) creg[i] = 0.0f;
        for (int i = tid; i < HROWS * 64; i += 512) { hlds[0][i] = (f16)0; hlds[1][i] = (f16)0; }
    } else {
        // seed h(8) window from global (rr <-> pos n0-HALO-1+rr), OOB -> 0
        for (int i = tid; i < HROWS * 8; i += 512) {
            int rr = i >> 3, c = i & 7;
            int pos = n0 - HALO - 1 + rr;
            half8 v = {};
            if (pos >= 0 && pos < NNP)
                v = *(const half8*)(h_glob + ((size_t)b * NNP + pos) * HID + c * 8);
            *(half8*)(hlds[0] + hadr(rr, c)) = v;
        }
        // hlds[1]: only halo rows 0 / HROWS-1 are read before being written
        for (int i = tid; i < 2 * 64; i += 512) {
            int rr = (i >= 64) ? (HROWS - 1) : 0;
            hlds[1][rr * 64 + (i & 63)] = (f16)0;
        }
#pragma unroll
        for (int ms = 0; ms < NMS; ++ms)
#pragma unroll
            for (int j = 0; j < 2; ++j) {
                int r   = lowm ? j : 2 + j;
                int pos = n0 - HALO + ms * 16 + kg * 4 + r;
                creg[ms * 2 + j] = (pos >= 0 && pos < NNP)
                    ? c_glob[((size_t)b * NNP + pos) * HID + hid] : 0.0f;
            }
    }

#pragma unroll 1
    for (int s = s0; s < s0 + 8; ++s) {
        __syncthreads();   // step s's reads vs step s-1's writes (and init)
        const f16* hrd = hlds[s & 1];
        f16*       hwr = hlds[(s & 1) ^ 1];
        const f16* xts = xt + (size_t)(s - s0) * WCMP * 8;

        floatx4 accA[2], accB[2];
#define MF(MS, A)  do_mfma<MS>(hrd, xts, bf, accb0, accb1, A, m, kg)
#define EP(MS, A)  do_epi<MS>(hwr, A, creg, m, kg, wave, lowm, edge, n0)
        if (wave < 4) {
            MF(0, accA);
            MF(1, accB); EP(0, accA);
            MF(2, accA); EP(1, accB);
            MF(3, accB); EP(2, accA);
            MF(4, accA); EP(3, accB);
            MF(5, accB); EP(4, accA);
            MF(6, accA); EP(5, accB);
            MF(7, accB); EP(6, accA);
            MF(8, accA); EP(7, accB);
            EP(8, accA);
        } else {
            MF(4, accA);
            MF(5, accB); EP(4, accA);
            MF(6, accA); EP(5, accB);
            MF(7, accB); EP(6, accA);
            MF(8, accA); EP(7, accB);
            MF(0, accB); EP(8, accA);
            MF(1, accA); EP(0, accB);
            MF(2, accB); EP(1, accA);
            MF(3, accA); EP(2, accB);
            EP(3, accA);
        }
#undef MF
#undef EP
    }
    __syncthreads();   // last step's hwr (= hlds[0]) complete

    // h(s0+8) is in hlds[0] (last step is odd); valid rows rr = row+HALO+1.
    for (int i = tid; i < WOUT * 8; i += 512) {
        int row = i >> 3, c = i & 7;
        half8 v = *(const half8*)(hlds[0] + hadr(row + HALO + 1, c));
        *(half8*)(h_glob + ((size_t)b * NNP + n0 + row) * HID + c * 8) = v;
    }
    if (phase == 0) {
        // persist c(8) for valid rows
#pragma unroll
        for (int ms = 0; ms < NMS; ++ms)
#pragma unroll
            for (int j = 0; j < 2; ++j) {
                int r   = lowm ? j : 2 + j;
                int rit = ms * 16 + kg * 4 + r;
                int pos = n0 - HALO + rit;
                if (rit >= HALO && rit < HALO + WOUT && pos >= 0 && pos < NNP)
                    c_glob[((size_t)b * NNP + pos) * HID + hid] = creg[ms * 2 + j];
            }
    }
}

// ---------------------------------------------------------------------------
// fc: out[b,t,n] = sum_hid h[b][n][hid]*fc_w[hid] + fc_b, broadcast over t
// ---------------------------------------------------------------------------
__global__ void fc_kernel(const f16* __restrict__ h, const float* __restrict__ fc_w,
                          const float* __restrict__ fc_b, float* __restrict__ out) {
    int idx = blockIdx.x * 256 + threadIdx.x;      // b*NNP + n
    const half8* hp = (const half8*)(h + (size_t)idx * HID);
    float s = 0.0f;
#pragma unroll
    for (int q = 0; q < 8; ++q) {
        half8 v = hp[q];
#pragma unroll
        for (int e = 0; e < 8; ++e) s += (float)v[e] * fc_w[q * 8 + e];
    }
    s += fc_b[0];
    int b = idx >> 12, n = idx & (NNP - 1);
#pragma unroll
    for (int t = 0; t < TSN; ++t) out[((size_t)b * TSN + t) * NNP + n] = s;
}

extern "C" void kernel_launch(void* const* d_in, const int* in_sizes, int n_in,
                              void* d_out, int out_size, void* d_ws, size_t ws_size,
                              hipStream_t stream) {
    const float* x      = (const float*)d_in[0];
    const float* conv_w = (const float*)d_in[1];
    const float* conv_b = (const float*)d_in[2];
    const float* fc_w   = (const float*)d_in[3];
    const float* fc_b   = (const float*)d_in[4];
    float* out = (float*)d_out;

    char* ws = (char*)d_ws;
    const size_t hbytes = (size_t)BB * NNP * HID * sizeof(f16);     // 8.39 MB
    f16*   wpack  = (f16*)ws;                                       // 112 KiB
    f16*   h_glob = (f16*)(ws + 131072);
    float* c_glob = (float*)(ws + 131072 + hbytes);                 // 16.8 MB

    pack_w_kernel<<<(4 * 64 * KPK + 255) / 256, 256, 0, stream>>>(conv_w, wpack);
    lstm_kernel<<<BB * NTIL, 512, 0, stream>>>(x, wpack, conv_b, h_glob, c_glob, 0);
    lstm_kernel<<<BB * NTIL, 512, 0, stream>>>(x, wpack, conv_b, h_glob, c_glob, 1);
    fc_kernel<<<BB * NNP / 256, 256, 0, stream>>>(h_glob, fc_w, fc_b, out);
}